// Round 7
// baseline (711.251 us; speedup 1.0000x reference)
//
#include <hip/hip_runtime.h>

#define NWIN 1024
#define WIN 128
#define DM 128
#define NTOT (NWIN*WIN)

typedef __bf16 bf16;
typedef __bf16 bf16x2 __attribute__((ext_vector_type(2)));
typedef __bf16 bf16x4 __attribute__((ext_vector_type(4)));
typedef __bf16 bf16x8 __attribute__((ext_vector_type(8)));
typedef float f32x4 __attribute__((ext_vector_type(4)));
typedef float f32x16 __attribute__((ext_vector_type(16)));

#define MFMA16(a,b,c) __builtin_amdgcn_mfma_f32_16x16x32_bf16(a,b,c,0,0,0)
#define MFMA32(a,b,c) __builtin_amdgcn_mfma_f32_32x32x16_bf16(a,b,c,0,0,0)

// ---------------- small prep kernels ----------------

__global__ void k_cvt_weights(const float* __restrict__ inproj, const float* __restrict__ outproj,
                              const float* __restrict__ w1, const float* __restrict__ w2,
                              bf16* __restrict__ whi, bf16* __restrict__ wlo) {
    int i = blockIdx.x * 256 + threadIdx.x;   // grid exactly 131072
    float v;
    if (i < 49152)       v = inproj[i];
    else if (i < 65536)  v = outproj[i - 49152];
    else if (i < 98304)  v = w1[i - 65536];
    else                 v = w2[i - 98304];
    bf16 h = (bf16)v;
    whi[i] = h;
    wlo[i] = (bf16)(v - (float)h);
}

__global__ void k_init_maps(int* __restrict__ mq, int* __restrict__ mkv, int* __restrict__ flag) {
    int i = blockIdx.x * 256 + threadIdx.x;
    if (i == 0) *flag = 0;
    if (i < NTOT) { mq[i] = -1; mkv[i] = -1; }
}

__global__ void k_fill_maps(const int* __restrict__ inds, const int* __restrict__ keep, int n,
                            const int* __restrict__ inds_p, const int* __restrict__ keep_p, int np,
                            int* __restrict__ mq, int* __restrict__ mkv) {
    int j = blockIdx.x * 256 + threadIdx.x;
    if (j < n)  mq[inds[j]]    = keep[j];
    if (j < np) mkv[inds_p[j]] = keep_p[j];
}

// Detect mask storage: if any int32 word of the mask is outside {0,1}, the bools
// are byte-packed (e.g. 0x01010101); else they are one int32 per element.
__global__ void k_mask_detect(const int* __restrict__ kpm_i, int* __restrict__ flag) {
    int i = blockIdx.x * 256 + threadIdx.x;   // grid 128 -> 32768 ints = 131072 bytes
    int v = kpm_i[i];
    if (v != 0 && v != 1) atomicOr(flag, 1);
}

__global__ void k_mask_expand(const int* __restrict__ kpm_i, const unsigned char* __restrict__ kpm_b,
                              const int* __restrict__ flag, unsigned char* __restrict__ kmask) {
    int i = blockIdx.x * 256 + threadIdx.x;   // grid 512 -> 131072
    int byte_mode = *flag;
    kmask[i] = byte_mode ? (kpm_b[i] != 0) : (kpm_i[i] != 0);
}

__global__ void k_copy4(const float4* __restrict__ s, float4* __restrict__ d, int n4) {
    int i = blockIdx.x * 256 + threadIdx.x;
    int stride = gridDim.x * 256;
    for (; i < n4; i += stride) d[i] = s[i];
}

// 3-term split GEMM (one 16-row tile): acc += (Ah+Al)@(Bh+Bl)^T, dropping Al*Bl.
__device__ __forceinline__ void proj3p(const bf16* __restrict__ Xh, const bf16* __restrict__ Xl,
                                       const bf16* __restrict__ WH, const bf16* __restrict__ WL,
                                       int l15, int g16, f32x4 acc[8]) {
    #pragma unroll
    for (int ks = 0; ks < 4; ks++) {
        bf16x8 ah = *(const bf16x8*)(Xh + l15 * 136 + ks*32 + g16*8);
        bf16x8 al = *(const bf16x8*)(Xl + l15 * 136 + ks*32 + g16*8);
        #pragma unroll
        for (int tn = 0; tn < 8; tn++) {
            bf16x8 bh = *(const bf16x8*)(WH + (size_t)(16*tn + l15) * DM + ks*32 + g16*8);
            bf16x8 bl = *(const bf16x8*)(WL + (size_t)(16*tn + l15) * DM + ks*32 + g16*8);
            acc[tn] = MFMA16(ah, bh, acc[tn]);
            acc[tn] = MFMA16(ah, bl, acc[tn]);
            acc[tn] = MFMA16(al, bh, acc[tn]);
        }
    }
}

// ---------------- QKV projection (64-row panel per block), split precision ----------------
// Q[w][tok][128], K[w][tok][128] row-major bf16; Vt[w][dim][key] transposed bf16.
// Static LDS = 53248 B (<64K): Xhi[64*136] + Xlo[64*136] + Bb[9216].
__global__ __launch_bounds__(256) void k_qkv(
    const float* __restrict__ src, const float* __restrict__ src_prv,
    const float* __restrict__ pos, const float* __restrict__ pos_prv,
    const bf16* __restrict__ whi, const bf16* __restrict__ wlo,
    const float* __restrict__ bqkv,
    const int* __restrict__ mq, const int* __restrict__ mkv,
    bf16* __restrict__ Qg, bf16* __restrict__ Kg, bf16* __restrict__ Vtg)
{
    const int blk = blockIdx.x;            // 2048 blocks, 64 rows each
    const int rbase = blk * 64;
    const int w = blk >> 1;                // window index
    const int kb = (blk & 1) * 64;         // key offset within window
    const int tid = threadIdx.x;
    const int lane = tid & 63, wv = tid >> 6;
    const int l15 = lane & 15, g16 = lane >> 4;
    __shared__ bf16 Xhi[64*136];
    __shared__ bf16 Xlo[64*136];
    __shared__ bf16 Bb[9216];              // Q/K staging [64][136] or Vt staging [128][72]

    const int srow = tid >> 2, sq4 = tid & 3;   // 4 threads per row, 32 cols each

    // ---- stage x_q = gather(src) + pos, hi/lo ----
    {
        const int p = rbase + srow;
        const int g = mq[p];
        const float4* pr = (const float4*)(pos + (size_t)p * DM + sq4 * 32);
        const float4* sr = (g >= 0) ? (const float4*)(src + (size_t)g * DM + sq4 * 32) : nullptr;
        bf16* xh = Xhi + srow * 136 + sq4 * 32;
        bf16* xl = Xlo + srow * 136 + sq4 * 32;
        #pragma unroll
        for (int i = 0; i < 8; i++) {
            float4 v = pr[i];
            if (sr) { float4 s4 = sr[i]; v.x += s4.x; v.y += s4.y; v.z += s4.z; v.w += s4.w; }
            bf16x4 h = { (bf16)v.x, (bf16)v.y, (bf16)v.z, (bf16)v.w };
            bf16x4 l = { (bf16)(v.x - (float)h.x), (bf16)(v.y - (float)h.y),
                         (bf16)(v.z - (float)h.z), (bf16)(v.w - (float)h.w) };
            *(bf16x4*)(xh + i * 4) = h;
            *(bf16x4*)(xl + i * 4) = l;
        }
    }
    __syncthreads();

    // ---- GEMM Q (wave wv owns rows 16*wv..+15) ----
    f32x4 qa[8];
    for (int tn = 0; tn < 8; tn++) qa[tn] = {};
    proj3p(Xhi + 16*wv*136, Xlo + 16*wv*136, whi, wlo, l15, g16, qa);
    #pragma unroll
    for (int tn = 0; tn < 8; tn++) {
        float bias = bqkv[16*tn + l15];
        #pragma unroll
        for (int r = 0; r < 4; r++)
            Bb[(16*wv + 4*g16 + r) * 136 + 16*tn + l15] = (bf16)(qa[tn][r] + bias);
    }
    __syncthreads();   // X reads done; Bb(Q) written

    // ---- store Q from Bb; restage x_v = grid_prv (NO pos) ----
    {
        const int p = rbase + srow;
        const int g = mkv[p];
        bf16* xh = Xhi + srow * 136 + sq4 * 32;
        bf16* xl = Xlo + srow * 136 + sq4 * 32;
        if (g >= 0) {
            const float4* sr = (const float4*)(src_prv + (size_t)g * DM + sq4 * 32);
            #pragma unroll
            for (int i = 0; i < 8; i++) {
                float4 v = sr[i];
                bf16x4 h = { (bf16)v.x, (bf16)v.y, (bf16)v.z, (bf16)v.w };
                bf16x4 l = { (bf16)(v.x - (float)h.x), (bf16)(v.y - (float)h.y),
                             (bf16)(v.z - (float)h.z), (bf16)(v.w - (float)h.w) };
                *(bf16x4*)(xh + i * 4) = h;
                *(bf16x4*)(xl + i * 4) = l;
            }
        } else {
            bf16x4 z = { (bf16)0.f, (bf16)0.f, (bf16)0.f, (bf16)0.f };
            #pragma unroll
            for (int i = 0; i < 8; i++) { *(bf16x4*)(xh + i * 4) = z; *(bf16x4*)(xl + i * 4) = z; }
        }
    }
    #pragma unroll
    for (int it = 0; it < 4; it++) {
        int c = it * 256 + tid;
        int row = c >> 4, off = (c & 15) * 8;
        *(bf16x8*)(Qg + (size_t)(rbase + row) * DM + off) = *(const bf16x8*)(Bb + row*136 + off);
    }
    __syncthreads();   // x_v staged; Bb(Q) reads done

    // ---- GEMM V ----
    f32x4 va[8];
    for (int tn = 0; tn < 8; tn++) va[tn] = {};
    proj3p(Xhi + 16*wv*136, Xlo + 16*wv*136, whi + 256*DM, wlo + 256*DM, l15, g16, va);
    #pragma unroll
    for (int tn = 0; tn < 8; tn++) {
        float bias = bqkv[256 + 16*tn + l15];
        int dim = 16*tn + l15;
        bf16x4 b = { (bf16)(va[tn][0] + bias), (bf16)(va[tn][1] + bias),
                     (bf16)(va[tn][2] + bias), (bf16)(va[tn][3] + bias) };
        *(bf16x4*)(Bb + dim * 72 + 16*wv + 4*g16) = b;   // Vt staging [128][72]
    }
    __syncthreads();   // X reads done; Bb(Vt) written

    // ---- store Vt from Bb; X += pos_prv in place (hi/lo refresh) ----
    {
        const int p = rbase + srow;
        const float4* pr = (const float4*)(pos_prv + (size_t)p * DM + sq4 * 32);
        bf16* xh = Xhi + srow * 136 + sq4 * 32;
        bf16* xl = Xlo + srow * 136 + sq4 * 32;
        #pragma unroll
        for (int i = 0; i < 8; i++) {
            float4 v = pr[i];
            bf16x4 ch = *(const bf16x4*)(xh + i * 4);
            bf16x4 cl = *(const bf16x4*)(xl + i * 4);
            float f0 = (float)ch.x + (float)cl.x + v.x;
            float f1 = (float)ch.y + (float)cl.y + v.y;
            float f2 = (float)ch.z + (float)cl.z + v.z;
            float f3 = (float)ch.w + (float)cl.w + v.w;
            bf16x4 h = { (bf16)f0, (bf16)f1, (bf16)f2, (bf16)f3 };
            bf16x4 l = { (bf16)(f0 - (float)h.x), (bf16)(f1 - (float)h.y),
                         (bf16)(f2 - (float)h.z), (bf16)(f3 - (float)h.w) };
            *(bf16x4*)(xh + i * 4) = h;
            *(bf16x4*)(xl + i * 4) = l;
        }
    }
    #pragma unroll
    for (int it = 0; it < 4; it++) {
        int c = it * 256 + tid;
        int dim = c >> 3, off = (c & 7) * 8;
        *(bf16x8*)(Vtg + ((size_t)w * 128 + dim) * 128 + kb + off) = *(const bf16x8*)(Bb + dim*72 + off);
    }
    __syncthreads();   // x_k staged; Bb(Vt) reads done

    // ---- GEMM K ----
    f32x4 ka[8];
    for (int tn = 0; tn < 8; tn++) ka[tn] = {};
    proj3p(Xhi + 16*wv*136, Xlo + 16*wv*136, whi + 128*DM, wlo + 128*DM, l15, g16, ka);
    #pragma unroll
    for (int tn = 0; tn < 8; tn++) {
        float bias = bqkv[128 + 16*tn + l15];
        #pragma unroll
        for (int r = 0; r < 4; r++)
            Bb[(16*wv + 4*g16 + r) * 136 + 16*tn + l15] = (bf16)(ka[tn][r] + bias);
    }
    __syncthreads();
    #pragma unroll
    for (int it = 0; it < 4; it++) {
        int c = it * 256 + tid;
        int row = c >> 4, off = (c & 15) * 8;
        *(bf16x8*)(Kg + (size_t)(rbase + row) * DM + off) = *(const bf16x8*)(Bb + row*136 + off);
    }
}

// ---------------- attention + out_proj + scatter-add (per window) ----------------
__global__ __launch_bounds__(256) void k_attn(
    const bf16* __restrict__ Qg, const bf16* __restrict__ Kg, const bf16* __restrict__ Vtg,
    const bf16* __restrict__ whi, const bf16* __restrict__ wlo, const float* __restrict__ ob,
    const unsigned char* __restrict__ kmask, const int* __restrict__ mq,
    float* __restrict__ x1)
{
    const int w = blockIdx.x;
    const int tid = threadIdx.x;
    const int lane = tid & 63, wv = tid >> 6;
    const int l15 = lane & 15, g16 = lane >> 4;
    const int l31 = lane & 31, h32 = lane >> 5;
    __shared__ bf16 P[4][32 * 136];
    bf16* myP = &P[wv][0];

    bool msk[4];
    #pragma unroll
    for (int kt = 0; kt < 4; kt++) msk[kt] = kmask[w * WIN + 32*kt + l31] != 0;

    const bf16* Qw = Qg + (size_t)w * WIN * DM;
    const bf16* Kw = Kg + (size_t)w * WIN * DM;
    const bf16* Vw = Vtg + (size_t)w * WIN * DM;

    f32x4 oacc[8][2];
    for (int h = 0; h < 8; h++) { oacc[h][0] = {}; oacc[h][1] = {}; }

    #pragma unroll
    for (int h = 0; h < 8; h++) {
        // S = Q_h @ K_h^T  (32 query rows per wave, 4 key tiles, K=16 per MFMA)
        bf16x8 qf = *(const bf16x8*)(Qw + (size_t)(32*wv + l31) * DM + 16*h + h32*8);
        f32x16 s[4];
        #pragma unroll
        for (int kt = 0; kt < 4; kt++) {
            bf16x8 kf = *(const bf16x8*)(Kw + (size_t)(32*kt + l31) * DM + 16*h + h32*8);
            f32x16 z = {};
            s[kt] = MFMA32(qf, kf, z);
        }
        #pragma unroll
        for (int kt = 0; kt < 4; kt++) {
            #pragma unroll
            for (int r = 0; r < 16; r++)
                s[kt][r] = msk[kt] ? -1e9f : s[kt][r] * 0.25f;
        }
        // row softmax (row = (r&3)+8*(r>>2)+4*h32, cols across 32 lanes x 4 tiles)
        #pragma unroll
        for (int r = 0; r < 16; r++) {
            float m = fmaxf(fmaxf(s[0][r], s[1][r]), fmaxf(s[2][r], s[3][r]));
            #pragma unroll
            for (int d = 1; d <= 16; d <<= 1) m = fmaxf(m, __shfl_xor(m, d));
            float e0 = __expf(s[0][r] - m), e1 = __expf(s[1][r] - m);
            float e2 = __expf(s[2][r] - m), e3 = __expf(s[3][r] - m);
            float sum = e0 + e1 + e2 + e3;
            #pragma unroll
            for (int d = 1; d <= 16; d <<= 1) sum += __shfl_xor(sum, d);
            float inv = __builtin_amdgcn_rcpf(sum);
            int qrow = (r & 3) + 8 * (r >> 2) + 4 * h32;
            myP[qrow * 136 +      l31] = (bf16)(e0 * inv);
            myP[qrow * 136 + 32 + l31] = (bf16)(e1 * inv);
            myP[qrow * 136 + 64 + l31] = (bf16)(e2 * inv);
            myP[qrow * 136 + 96 + l31] = (bf16)(e3 * inv);
        }
        // O_h += P @ V_h   (B-operand = Vt rows, 8 contiguous keys)
        #pragma unroll
        for (int ks = 0; ks < 4; ks++) {
            bf16x8 p0 = *(const bf16x8*)(myP + (l15     ) * 136 + ks*32 + g16*8);
            bf16x8 p1 = *(const bf16x8*)(myP + (16 + l15) * 136 + ks*32 + g16*8);
            bf16x8 vf = *(const bf16x8*)(Vw + (size_t)(16*h + l15) * DM + ks*32 + g16*8);
            oacc[h][0] = MFMA16(p0, vf, oacc[h][0]);
            oacc[h][1] = MFMA16(p1, vf, oacc[h][1]);
        }
    }

    // O -> LDS (reuse P region), then out_proj (2-term: Wo hi + lo)
    #pragma unroll
    for (int h = 0; h < 8; h++) {
        #pragma unroll
        for (int tq = 0; tq < 2; tq++) {
            #pragma unroll
            for (int r = 0; r < 4; r++)
                myP[(16*tq + 4*g16 + r) * 136 + 16*h + l15] = (bf16)oacc[h][tq][r];
        }
    }

    const bf16* Woh = whi + 49152;
    const bf16* Wol = wlo + 49152;
    f32x4 oc[2][8];
    for (int tq = 0; tq < 2; tq++)
        for (int tn = 0; tn < 8; tn++)
            oc[tq][tn] = {};
    #pragma unroll
    for (int ks = 0; ks < 4; ks++) {
        bf16x8 a0 = *(const bf16x8*)(myP + (l15     ) * 136 + ks*32 + g16*8);
        bf16x8 a1 = *(const bf16x8*)(myP + (16 + l15) * 136 + ks*32 + g16*8);
        #pragma unroll
        for (int tn = 0; tn < 8; tn++) {
            bf16x8 bh = *(const bf16x8*)(Woh + (size_t)(16*tn + l15) * DM + ks*32 + g16*8);
            bf16x8 bl = *(const bf16x8*)(Wol + (size_t)(16*tn + l15) * DM + ks*32 + g16*8);
            oc[0][tn] = MFMA16(a0, bh, oc[0][tn]);
            oc[0][tn] = MFMA16(a0, bl, oc[0][tn]);
            oc[1][tn] = MFMA16(a1, bh, oc[1][tn]);
            oc[1][tn] = MFMA16(a1, bl, oc[1][tn]);
        }
    }

    float obv[8];
    #pragma unroll
    for (int tn = 0; tn < 8; tn++) obv[tn] = ob[16*tn + l15];
    #pragma unroll
    for (int tq = 0; tq < 2; tq++) {
        #pragma unroll
        for (int r = 0; r < 4; r++) {
            int qrow = 32*wv + 16*tq + 4*g16 + r;
            int g = mq[w * WIN + qrow];
            if (g < 0) continue;
            float* orow = x1 + (size_t)g * DM;
            #pragma unroll
            for (int tn = 0; tn < 8; tn++)
                orow[16*tn + l15] += oc[tq][tn][r] + obv[tn];
        }
    }
}

// ---------------- fused LN1 + FFN + residual + LN2 (64 rows/block, 16 rows/wave) ----------------
// Static LDS: Hb only (33792 B). Residual LN1-output recomputed exactly in f32 via
// global x1 re-read + shfl-broadcast row stats.
__global__ __launch_bounds__(256) void k_ffn(
    const float* __restrict__ x1, const bf16* __restrict__ whi, const bf16* __restrict__ wlo,
    const float* __restrict__ g1, const float* __restrict__ b1ln,
    const float* __restrict__ fb1, const float* __restrict__ fb2,
    const float* __restrict__ g2, const float* __restrict__ b2ln,
    float* __restrict__ out)
{
    const int tid = threadIdx.x;
    const int lane = tid & 63, wv = tid >> 6;
    const int l15 = lane & 15, g16 = lane >> 4;
    const int rbase = blockIdx.x * 64 + wv * 16;
    __shared__ bf16 Hb[4][16 * 264];
    bf16* myH = &Hb[wv][0];
    const bf16* W1h = whi + 65536;
    const bf16* W1l = wlo + 65536;
    const bf16* W2h = whi + 98304;
    const bf16* W2l = wlo + 98304;

    // ---- LN1 stats: lane owns row rbase+l15, 32 of its cols ----
    float xv[4][8];
    float sum = 0.f, sq = 0.f;
    const float* xrow = x1 + (size_t)(rbase + l15) * DM;
    #pragma unroll
    for (int ks = 0; ks < 4; ks++) {
        float4 a = *(const float4*)(xrow + ks*32 + g16*8);
        float4 b = *(const float4*)(xrow + ks*32 + g16*8 + 4);
        xv[ks][0]=a.x; xv[ks][1]=a.y; xv[ks][2]=a.z; xv[ks][3]=a.w;
        xv[ks][4]=b.x; xv[ks][5]=b.y; xv[ks][6]=b.z; xv[ks][7]=b.w;
        sum += a.x+a.y+a.z+a.w + b.x+b.y+b.z+b.w;
        sq  += a.x*a.x+a.y*a.y+a.z*a.z+a.w*a.w + b.x*b.x+b.y*b.y+b.z*b.z+b.w*b.w;
    }
    sum += __shfl_xor(sum, 16); sum += __shfl_xor(sum, 32);
    sq  += __shfl_xor(sq, 16);  sq  += __shfl_xor(sq, 32);
    float mean = sum * (1.f/128.f);
    float var  = sq * (1.f/128.f) - mean * mean;
    float rstd = rsqrtf(var + 1e-5f);

    // ---- y = LN1(x) in f32; hi/lo A-frags ----
    bf16x8 ah[4], al[4];
    #pragma unroll
    for (int ks = 0; ks < 4; ks++) {
        #pragma unroll
        for (int j = 0; j < 8; j++) {
            int col = ks*32 + g16*8 + j;
            float y = (xv[ks][j] - mean) * rstd * g1[col] + b1ln[col];
            bf16 h = (bf16)y;
            ah[ks][j] = h;
            al[ks][j] = (bf16)(y - (float)h);
        }
    }

    // ---- GEMM1 (3-term split) + ReLU -> Hb ----
    f32x4 h1[16];
    for (int tn = 0; tn < 16; tn++) h1[tn] = {};
    #pragma unroll
    for (int ks = 0; ks < 4; ks++) {
        #pragma unroll
        for (int tn = 0; tn < 16; tn++) {
            bf16x8 bh = *(const bf16x8*)(W1h + (size_t)(16*tn + l15) * DM + ks*32 + g16*8);
            bf16x8 bl = *(const bf16x8*)(W1l + (size_t)(16*tn + l15) * DM + ks*32 + g16*8);
            h1[tn] = MFMA16(ah[ks], bh, h1[tn]);
            h1[tn] = MFMA16(ah[ks], bl, h1[tn]);
            h1[tn] = MFMA16(al[ks], bh, h1[tn]);
        }
    }
    #pragma unroll
    for (int tn = 0; tn < 16; tn++) {
        float bias = fb1[16*tn + l15];
        #pragma unroll
        for (int r = 0; r < 4; r++) {
            float v = fmaxf(h1[tn][r] + bias, 0.f);
            myH[(4*g16 + r) * 264 + 16*tn + l15] = (bf16)v;
        }
    }

    // ---- GEMM2 (2-term: W2 hi + lo) ----
    f32x4 o[8];
    for (int tn = 0; tn < 8; tn++) o[tn] = {};
    #pragma unroll
    for (int ks = 0; ks < 8; ks++) {
        bf16x8 a = *(const bf16x8*)(myH + l15 * 264 + ks*32 + g16*8);
        #pragma unroll
        for (int tn = 0; tn < 8; tn++) {
            bf16x8 bh = *(const bf16x8*)(W2h + (size_t)(16*tn + l15) * 256 + ks*32 + g16*8);
            bf16x8 bl = *(const bf16x8*)(W2l + (size_t)(16*tn + l15) * 256 + ks*32 + g16*8);
            o[tn] = MFMA16(a, bh, o[tn]);
            o[tn] = MFMA16(a, bl, o[tn]);
        }
    }

    // ---- residual: recompute y for C-layout rows (exact f32), + LN2 ----
    #pragma unroll
    for (int r = 0; r < 4; r++) {
        int rw = 4*g16 + r;                       // row within wave tile
        int row = rbase + rw;
        float bm = __shfl(mean, rw);              // stats live in lanes 0..15
        float br = __shfl(rstd, rw);
        float tmp[8];
        float s2 = 0.f, q2 = 0.f;
        #pragma unroll
        for (int tn = 0; tn < 8; tn++) {
            int col = 16*tn + l15;
            float xr = x1[(size_t)row * DM + col];
            float y  = (xr - bm) * br * g1[col] + b1ln[col];
            float v  = o[tn][r] + fb2[col] + y;
            tmp[tn] = v; s2 += v; q2 += v * v;
        }
        #pragma unroll
        for (int d = 1; d <= 8; d <<= 1) { s2 += __shfl_xor(s2, d); q2 += __shfl_xor(q2, d); }
        float mean2 = s2 * (1.f/128.f);
        float var2  = q2 * (1.f/128.f) - mean2 * mean2;
        float rstd2 = rsqrtf(var2 + 1e-5f);
        #pragma unroll
        for (int tn = 0; tn < 8; tn++) {
            int col = 16*tn + l15;
            out[(size_t)row * DM + col] = (tmp[tn] - mean2) * rstd2 * g2[col] + b2ln[col];
        }
    }
}

// ---------------- launcher ----------------
extern "C" void kernel_launch(void* const* d_in, const int* in_sizes, int n_in,
                              void* d_out, int out_size, void* d_ws, size_t ws_size,
                              hipStream_t stream)
{
    const float* src      = (const float*)d_in[0];
    const float* src_prv  = (const float*)d_in[1];
    const float* pos      = (const float*)d_in[2];
    const float* pos_prv  = (const float*)d_in[3];
    const float* inpw     = (const float*)d_in[4];
    const float* inpb     = (const float*)d_in[5];
    const float* outpw    = (const float*)d_in[6];
    const float* outpb    = (const float*)d_in[7];
    const float* l1w      = (const float*)d_in[8];
    const float* l1b      = (const float*)d_in[9];
    const float* l2w      = (const float*)d_in[10];
    const float* l2b      = (const float*)d_in[11];
    const float* ln1g     = (const float*)d_in[12];
    const float* ln1b     = (const float*)d_in[13];
    const float* ln2g     = (const float*)d_in[14];
    const float* ln2b     = (const float*)d_in[15];
    const int* keep       = (const int*)d_in[16];
    const int* keep_p     = (const int*)d_in[17];
    const int* inds       = (const int*)d_in[18];
    const int* inds_p     = (const int*)d_in[19];
    const int n_inds = in_sizes[18], n_prv = in_sizes[19];

    char* wsb = (char*)d_ws;
    bf16* whi  = (bf16*)(wsb);                                  // 262144 B
    bf16* wlo  = (bf16*)(wsb + 262144);                         // 262144 B
    int*  mq   = (int*)(wsb + 524288);                          // 524288 B
    int*  mkv  = (int*)(wsb + 1048576);                         // 524288 B
    bf16* Qb   = (bf16*)(wsb + 1572864);                        // 33554432 B
    bf16* Kb   = (bf16*)(wsb + 1572864 + 33554432);             // 33554432 B
    bf16* Vtb  = (bf16*)(wsb + 1572864 + 2u*33554432);          // 33554432 B
    unsigned char* kmask = (unsigned char*)(wsb + 1572864 + 3u*33554432);  // 131072 B
    int* mflag = (int*)(wsb + 1572864 + 3u*33554432 + 131072);  // 4 B
    float* x1 = (float*)d_out;

    k_cvt_weights<<<512, 256, 0, stream>>>(inpw, outpw, l1w, l2w, whi, wlo);
    k_init_maps<<<512, 256, 0, stream>>>(mq, mkv, mflag);
    int mmax = n_inds > n_prv ? n_inds : n_prv;
    k_fill_maps<<<(mmax + 255) / 256, 256, 0, stream>>>(inds, keep, n_inds, inds_p, keep_p, n_prv, mq, mkv);
    k_mask_detect<<<128, 256, 0, stream>>>((const int*)d_in[20], mflag);
    k_mask_expand<<<512, 256, 0, stream>>>((const int*)d_in[20], (const unsigned char*)d_in[20], mflag, kmask);
    k_copy4<<<2048, 256, 0, stream>>>((const float4*)src, (float4*)x1, NTOT * DM / 4);
    k_qkv<<<NTOT / 64, 256, 0, stream>>>(src, src_prv, pos, pos_prv, whi, wlo, inpb, mq, mkv, Qb, Kb, Vtb);
    k_attn<<<NWIN, 256, 0, stream>>>(Qb, Kb, Vtb, whi, wlo, outpb, kmask, mq, x1);
    k_ffn<<<NTOT / 64, 256, 0, stream>>>(x1, whi, wlo, ln1g, ln1b, l1b, l2b, ln2g, ln2b, (float*)d_out);
}

// Round 8
// 588.472 us; speedup vs baseline: 1.2086x; 1.2086x over previous
//
#include <hip/hip_runtime.h>

#define NWIN 1024
#define WIN 128
#define DM 128
#define NTOT (NWIN*WIN)

typedef __bf16 bf16;
typedef __bf16 bf16x2 __attribute__((ext_vector_type(2)));
typedef __bf16 bf16x4 __attribute__((ext_vector_type(4)));
typedef __bf16 bf16x8 __attribute__((ext_vector_type(8)));
typedef float f32x4 __attribute__((ext_vector_type(4)));
typedef float f32x16 __attribute__((ext_vector_type(16)));

#define MFMA16(a,b,c) __builtin_amdgcn_mfma_f32_16x16x32_bf16(a,b,c,0,0,0)
#define MFMA32(a,b,c) __builtin_amdgcn_mfma_f32_32x32x16_bf16(a,b,c,0,0,0)

// ---------------- small prep kernels ----------------

__global__ void k_cvt_weights(const float* __restrict__ inproj, const float* __restrict__ outproj,
                              const float* __restrict__ w1, const float* __restrict__ w2,
                              bf16* __restrict__ whi, bf16* __restrict__ wlo) {
    int i = blockIdx.x * 256 + threadIdx.x;   // grid exactly 131072
    float v;
    if (i < 49152)       v = inproj[i];
    else if (i < 65536)  v = outproj[i - 49152];
    else if (i < 98304)  v = w1[i - 65536];
    else                 v = w2[i - 98304];
    bf16 h = (bf16)v;
    whi[i] = h;
    wlo[i] = (bf16)(v - (float)h);
}

__global__ void k_init_maps(int* __restrict__ mq, int* __restrict__ mkv, int* __restrict__ flag) {
    int i = blockIdx.x * 256 + threadIdx.x;
    if (i == 0) *flag = 0;
    if (i < NTOT) { mq[i] = -1; mkv[i] = -1; }
}

__global__ void k_fill_maps(const int* __restrict__ inds, const int* __restrict__ keep, int n,
                            const int* __restrict__ inds_p, const int* __restrict__ keep_p, int np,
                            int* __restrict__ mq, int* __restrict__ mkv) {
    int j = blockIdx.x * 256 + threadIdx.x;
    if (j < n)  mq[inds[j]]    = keep[j];
    if (j < np) mkv[inds_p[j]] = keep_p[j];
}

// Detect mask storage: if any int32 word of the mask is outside {0,1}, the bools
// are byte-packed (e.g. 0x01010101); else they are one int32 per element.
__global__ void k_mask_detect(const int* __restrict__ kpm_i, int* __restrict__ flag) {
    int i = blockIdx.x * 256 + threadIdx.x;   // grid 128 -> 32768 ints = 131072 bytes
    int v = kpm_i[i];
    if (v != 0 && v != 1) atomicOr(flag, 1);
}

__global__ void k_mask_expand(const int* __restrict__ kpm_i, const unsigned char* __restrict__ kpm_b,
                              const int* __restrict__ flag, unsigned char* __restrict__ kmask) {
    int i = blockIdx.x * 256 + threadIdx.x;   // grid 512 -> 131072
    int byte_mode = *flag;
    kmask[i] = byte_mode ? (kpm_b[i] != 0) : (kpm_i[i] != 0);
}

__global__ void k_copy4(const float4* __restrict__ s, float4* __restrict__ d, int n4) {
    int i = blockIdx.x * 256 + threadIdx.x;
    int stride = gridDim.x * 256;
    for (; i < n4; i += stride) d[i] = s[i];
}

// 3-term split GEMM (one 16-row tile): acc += (Ah+Al)@(Bh+Bl)^T, dropping Al*Bl.
__device__ __forceinline__ void proj3p(const bf16* __restrict__ Xh, const bf16* __restrict__ Xl,
                                       const bf16* __restrict__ WH, const bf16* __restrict__ WL,
                                       int l15, int g16, f32x4 acc[8]) {
    #pragma unroll
    for (int ks = 0; ks < 4; ks++) {
        bf16x8 ah = *(const bf16x8*)(Xh + l15 * 136 + ks*32 + g16*8);
        bf16x8 al = *(const bf16x8*)(Xl + l15 * 136 + ks*32 + g16*8);
        #pragma unroll
        for (int tn = 0; tn < 8; tn++) {
            bf16x8 bh = *(const bf16x8*)(WH + (size_t)(16*tn + l15) * DM + ks*32 + g16*8);
            bf16x8 bl = *(const bf16x8*)(WL + (size_t)(16*tn + l15) * DM + ks*32 + g16*8);
            acc[tn] = MFMA16(ah, bh, acc[tn]);
            acc[tn] = MFMA16(ah, bl, acc[tn]);
            acc[tn] = MFMA16(al, bh, acc[tn]);
        }
    }
}

// ---------------- QKV projection (64-row panel per block), split precision ----------------
// Q[w][tok][128], K[w][tok][128] row-major bf16; Vt[w][dim][key] transposed bf16.
// Static LDS = 53248 B (<64K): Xhi[64*136] + Xlo[64*136] + Bb[9216].
__global__ __launch_bounds__(256) void k_qkv(
    const float* __restrict__ src, const float* __restrict__ src_prv,
    const float* __restrict__ pos, const float* __restrict__ pos_prv,
    const bf16* __restrict__ whi, const bf16* __restrict__ wlo,
    const float* __restrict__ bqkv,
    const int* __restrict__ mq, const int* __restrict__ mkv,
    bf16* __restrict__ Qg, bf16* __restrict__ Kg, bf16* __restrict__ Vtg)
{
    const int blk = blockIdx.x;            // 2048 blocks, 64 rows each
    const int rbase = blk * 64;
    const int w = blk >> 1;                // window index
    const int kb = (blk & 1) * 64;         // key offset within window
    const int tid = threadIdx.x;
    const int lane = tid & 63, wv = tid >> 6;
    const int l15 = lane & 15, g16 = lane >> 4;
    __shared__ bf16 Xhi[64*136];
    __shared__ bf16 Xlo[64*136];
    __shared__ bf16 Bb[9216];              // Q/K staging [64][136] or Vt staging [128][72]

    const int srow = tid >> 2, sq4 = tid & 3;   // 4 threads per row, 32 cols each

    // ---- stage x_q = gather(src) + pos, hi/lo ----
    {
        const int p = rbase + srow;
        const int g = mq[p];
        const float4* pr = (const float4*)(pos + (size_t)p * DM + sq4 * 32);
        const float4* sr = (g >= 0) ? (const float4*)(src + (size_t)g * DM + sq4 * 32) : nullptr;
        bf16* xh = Xhi + srow * 136 + sq4 * 32;
        bf16* xl = Xlo + srow * 136 + sq4 * 32;
        #pragma unroll
        for (int i = 0; i < 8; i++) {
            float4 v = pr[i];
            if (sr) { float4 s4 = sr[i]; v.x += s4.x; v.y += s4.y; v.z += s4.z; v.w += s4.w; }
            bf16x4 h = { (bf16)v.x, (bf16)v.y, (bf16)v.z, (bf16)v.w };
            bf16x4 l = { (bf16)(v.x - (float)h.x), (bf16)(v.y - (float)h.y),
                         (bf16)(v.z - (float)h.z), (bf16)(v.w - (float)h.w) };
            *(bf16x4*)(xh + i * 4) = h;
            *(bf16x4*)(xl + i * 4) = l;
        }
    }
    __syncthreads();

    // ---- GEMM Q (wave wv owns rows 16*wv..+15) ----
    f32x4 qa[8];
    for (int tn = 0; tn < 8; tn++) qa[tn] = {};
    proj3p(Xhi + 16*wv*136, Xlo + 16*wv*136, whi, wlo, l15, g16, qa);
    #pragma unroll
    for (int tn = 0; tn < 8; tn++) {
        float bias = bqkv[16*tn + l15];
        #pragma unroll
        for (int r = 0; r < 4; r++)
            Bb[(16*wv + 4*g16 + r) * 136 + 16*tn + l15] = (bf16)(qa[tn][r] + bias);
    }
    __syncthreads();   // X reads done; Bb(Q) written

    // ---- store Q from Bb; restage x_v = grid_prv (NO pos) ----
    {
        const int p = rbase + srow;
        const int g = mkv[p];
        bf16* xh = Xhi + srow * 136 + sq4 * 32;
        bf16* xl = Xlo + srow * 136 + sq4 * 32;
        if (g >= 0) {
            const float4* sr = (const float4*)(src_prv + (size_t)g * DM + sq4 * 32);
            #pragma unroll
            for (int i = 0; i < 8; i++) {
                float4 v = sr[i];
                bf16x4 h = { (bf16)v.x, (bf16)v.y, (bf16)v.z, (bf16)v.w };
                bf16x4 l = { (bf16)(v.x - (float)h.x), (bf16)(v.y - (float)h.y),
                             (bf16)(v.z - (float)h.z), (bf16)(v.w - (float)h.w) };
                *(bf16x4*)(xh + i * 4) = h;
                *(bf16x4*)(xl + i * 4) = l;
            }
        } else {
            bf16x4 z = { (bf16)0.f, (bf16)0.f, (bf16)0.f, (bf16)0.f };
            #pragma unroll
            for (int i = 0; i < 8; i++) { *(bf16x4*)(xh + i * 4) = z; *(bf16x4*)(xl + i * 4) = z; }
        }
    }
    #pragma unroll
    for (int it = 0; it < 4; it++) {
        int c = it * 256 + tid;
        int row = c >> 4, off = (c & 15) * 8;
        *(bf16x8*)(Qg + (size_t)(rbase + row) * DM + off) = *(const bf16x8*)(Bb + row*136 + off);
    }
    __syncthreads();   // x_v staged; Bb(Q) reads done

    // ---- GEMM V ----
    f32x4 va[8];
    for (int tn = 0; tn < 8; tn++) va[tn] = {};
    proj3p(Xhi + 16*wv*136, Xlo + 16*wv*136, whi + 256*DM, wlo + 256*DM, l15, g16, va);
    #pragma unroll
    for (int tn = 0; tn < 8; tn++) {
        float bias = bqkv[256 + 16*tn + l15];
        int dim = 16*tn + l15;
        bf16x4 b = { (bf16)(va[tn][0] + bias), (bf16)(va[tn][1] + bias),
                     (bf16)(va[tn][2] + bias), (bf16)(va[tn][3] + bias) };
        *(bf16x4*)(Bb + dim * 72 + 16*wv + 4*g16) = b;   // Vt staging [128][72]
    }
    __syncthreads();   // X reads done; Bb(Vt) written

    // ---- store Vt from Bb; X += pos_prv in place (hi/lo refresh) ----
    {
        const int p = rbase + srow;
        const float4* pr = (const float4*)(pos_prv + (size_t)p * DM + sq4 * 32);
        bf16* xh = Xhi + srow * 136 + sq4 * 32;
        bf16* xl = Xlo + srow * 136 + sq4 * 32;
        #pragma unroll
        for (int i = 0; i < 8; i++) {
            float4 v = pr[i];
            bf16x4 ch = *(const bf16x4*)(xh + i * 4);
            bf16x4 cl = *(const bf16x4*)(xl + i * 4);
            float f0 = (float)ch.x + (float)cl.x + v.x;
            float f1 = (float)ch.y + (float)cl.y + v.y;
            float f2 = (float)ch.z + (float)cl.z + v.z;
            float f3 = (float)ch.w + (float)cl.w + v.w;
            bf16x4 h = { (bf16)f0, (bf16)f1, (bf16)f2, (bf16)f3 };
            bf16x4 l = { (bf16)(f0 - (float)h.x), (bf16)(f1 - (float)h.y),
                         (bf16)(f2 - (float)h.z), (bf16)(f3 - (float)h.w) };
            *(bf16x4*)(xh + i * 4) = h;
            *(bf16x4*)(xl + i * 4) = l;
        }
    }
    #pragma unroll
    for (int it = 0; it < 4; it++) {
        int c = it * 256 + tid;
        int dim = c >> 3, off = (c & 7) * 8;
        *(bf16x8*)(Vtg + ((size_t)w * 128 + dim) * 128 + kb + off) = *(const bf16x8*)(Bb + dim*72 + off);
    }
    __syncthreads();   // x_k staged; Bb(Vt) reads done

    // ---- GEMM K ----
    f32x4 ka[8];
    for (int tn = 0; tn < 8; tn++) ka[tn] = {};
    proj3p(Xhi + 16*wv*136, Xlo + 16*wv*136, whi + 128*DM, wlo + 128*DM, l15, g16, ka);
    #pragma unroll
    for (int tn = 0; tn < 8; tn++) {
        float bias = bqkv[128 + 16*tn + l15];
        #pragma unroll
        for (int r = 0; r < 4; r++)
            Bb[(16*wv + 4*g16 + r) * 136 + 16*tn + l15] = (bf16)(ka[tn][r] + bias);
    }
    __syncthreads();
    #pragma unroll
    for (int it = 0; it < 4; it++) {
        int c = it * 256 + tid;
        int row = c >> 4, off = (c & 15) * 8;
        *(bf16x8*)(Kg + (size_t)(rbase + row) * DM + off) = *(const bf16x8*)(Bb + row*136 + off);
    }
}

// ---------------- attention + out_proj + scatter-add (per window) ----------------
__global__ __launch_bounds__(256) void k_attn(
    const bf16* __restrict__ Qg, const bf16* __restrict__ Kg, const bf16* __restrict__ Vtg,
    const bf16* __restrict__ whi, const bf16* __restrict__ wlo, const float* __restrict__ ob,
    const unsigned char* __restrict__ kmask, const int* __restrict__ mq,
    float* __restrict__ x1)
{
    const int w = blockIdx.x;
    const int tid = threadIdx.x;
    const int lane = tid & 63, wv = tid >> 6;
    const int l15 = lane & 15, g16 = lane >> 4;
    const int l31 = lane & 31, h32 = lane >> 5;
    __shared__ bf16 P[4][32 * 136];
    bf16* myP = &P[wv][0];

    bool msk[4];
    #pragma unroll
    for (int kt = 0; kt < 4; kt++) msk[kt] = kmask[w * WIN + 32*kt + l31] != 0;

    const bf16* Qw = Qg + (size_t)w * WIN * DM;
    const bf16* Kw = Kg + (size_t)w * WIN * DM;
    const bf16* Vw = Vtg + (size_t)w * WIN * DM;

    f32x4 oacc[8][2];
    for (int h = 0; h < 8; h++) { oacc[h][0] = {}; oacc[h][1] = {}; }

    #pragma unroll
    for (int h = 0; h < 8; h++) {
        // S = Q_h @ K_h^T  (32 query rows per wave, 4 key tiles, K=16 per MFMA)
        bf16x8 qf = *(const bf16x8*)(Qw + (size_t)(32*wv + l31) * DM + 16*h + h32*8);
        f32x16 s[4];
        #pragma unroll
        for (int kt = 0; kt < 4; kt++) {
            bf16x8 kf = *(const bf16x8*)(Kw + (size_t)(32*kt + l31) * DM + 16*h + h32*8);
            f32x16 z = {};
            s[kt] = MFMA32(qf, kf, z);
        }
        #pragma unroll
        for (int kt = 0; kt < 4; kt++) {
            #pragma unroll
            for (int r = 0; r < 16; r++)
                s[kt][r] = msk[kt] ? -1e9f : s[kt][r] * 0.25f;
        }
        // row softmax (row = (r&3)+8*(r>>2)+4*h32, cols across 32 lanes x 4 tiles)
        #pragma unroll
        for (int r = 0; r < 16; r++) {
            float m = fmaxf(fmaxf(s[0][r], s[1][r]), fmaxf(s[2][r], s[3][r]));
            #pragma unroll
            for (int d = 1; d <= 16; d <<= 1) m = fmaxf(m, __shfl_xor(m, d));
            float e0 = __expf(s[0][r] - m), e1 = __expf(s[1][r] - m);
            float e2 = __expf(s[2][r] - m), e3 = __expf(s[3][r] - m);
            float sum = e0 + e1 + e2 + e3;
            #pragma unroll
            for (int d = 1; d <= 16; d <<= 1) sum += __shfl_xor(sum, d);
            float inv = __builtin_amdgcn_rcpf(sum);
            int qrow = (r & 3) + 8 * (r >> 2) + 4 * h32;
            myP[qrow * 136 +      l31] = (bf16)(e0 * inv);
            myP[qrow * 136 + 32 + l31] = (bf16)(e1 * inv);
            myP[qrow * 136 + 64 + l31] = (bf16)(e2 * inv);
            myP[qrow * 136 + 96 + l31] = (bf16)(e3 * inv);
        }
        // O_h += P @ V_h   (B-operand = Vt rows, 8 contiguous keys)
        #pragma unroll
        for (int ks = 0; ks < 4; ks++) {
            bf16x8 p0 = *(const bf16x8*)(myP + (l15     ) * 136 + ks*32 + g16*8);
            bf16x8 p1 = *(const bf16x8*)(myP + (16 + l15) * 136 + ks*32 + g16*8);
            bf16x8 vf = *(const bf16x8*)(Vw + (size_t)(16*h + l15) * DM + ks*32 + g16*8);
            oacc[h][0] = MFMA16(p0, vf, oacc[h][0]);
            oacc[h][1] = MFMA16(p1, vf, oacc[h][1]);
        }
    }

    // O -> LDS (reuse P region), then out_proj (2-term: Wo hi + lo)
    #pragma unroll
    for (int h = 0; h < 8; h++) {
        #pragma unroll
        for (int tq = 0; tq < 2; tq++) {
            #pragma unroll
            for (int r = 0; r < 4; r++)
                myP[(16*tq + 4*g16 + r) * 136 + 16*h + l15] = (bf16)oacc[h][tq][r];
        }
    }

    const bf16* Woh = whi + 49152;
    const bf16* Wol = wlo + 49152;
    f32x4 oc[2][8];
    for (int tq = 0; tq < 2; tq++)
        for (int tn = 0; tn < 8; tn++)
            oc[tq][tn] = {};
    #pragma unroll
    for (int ks = 0; ks < 4; ks++) {
        bf16x8 a0 = *(const bf16x8*)(myP + (l15     ) * 136 + ks*32 + g16*8);
        bf16x8 a1 = *(const bf16x8*)(myP + (16 + l15) * 136 + ks*32 + g16*8);
        #pragma unroll
        for (int tn = 0; tn < 8; tn++) {
            bf16x8 bh = *(const bf16x8*)(Woh + (size_t)(16*tn + l15) * DM + ks*32 + g16*8);
            bf16x8 bl = *(const bf16x8*)(Wol + (size_t)(16*tn + l15) * DM + ks*32 + g16*8);
            oc[0][tn] = MFMA16(a0, bh, oc[0][tn]);
            oc[0][tn] = MFMA16(a0, bl, oc[0][tn]);
            oc[1][tn] = MFMA16(a1, bh, oc[1][tn]);
            oc[1][tn] = MFMA16(a1, bl, oc[1][tn]);
        }
    }

    float obv[8];
    #pragma unroll
    for (int tn = 0; tn < 8; tn++) obv[tn] = ob[16*tn + l15];
    #pragma unroll
    for (int tq = 0; tq < 2; tq++) {
        #pragma unroll
        for (int r = 0; r < 4; r++) {
            int qrow = 32*wv + 16*tq + 4*g16 + r;
            int g = mq[w * WIN + qrow];
            if (g < 0) continue;
            float* orow = x1 + (size_t)g * DM;
            #pragma unroll
            for (int tn = 0; tn < 8; tn++)
                orow[16*tn + l15] += oc[tq][tn][r] + obv[tn];
        }
    }
}

// ---------------- fused LN1 + FFN + residual + LN2 (64 rows/block, 16 rows/wave) ----------------
// v3: plain-bf16 FFN GEMMs (attention-path bf16 dominates the error budget), GEMM1 in
// two 8-tn chunks to cut accumulator VGPRs, __launch_bounds__(256,4) to force <=128 VGPR
// -> 4 waves/SIMD (was 144 VGPR / 2 waves/SIMD / 286 us, latency-bound at 6% MfmaUtil).
// LN stats f32; residual LN1-output recomputed exactly in f32 (unchanged).
__global__ __launch_bounds__(256, 4) void k_ffn(
    const float* __restrict__ x1, const bf16* __restrict__ whi, const bf16* __restrict__ wlo,
    const float* __restrict__ g1, const float* __restrict__ b1ln,
    const float* __restrict__ fb1, const float* __restrict__ fb2,
    const float* __restrict__ g2, const float* __restrict__ b2ln,
    float* __restrict__ out)
{
    const int tid = threadIdx.x;
    const int lane = tid & 63, wv = tid >> 6;
    const int l15 = lane & 15, g16 = lane >> 4;
    const int rbase = blockIdx.x * 64 + wv * 16;
    __shared__ bf16 Hb[4][16 * 264];
    bf16* myH = &Hb[wv][0];
    const bf16* W1h = whi + 65536;
    const bf16* W2h = whi + 98304;

    // ---- LN1 stats: lane owns row rbase+l15, 32 of its cols ----
    float xv[4][8];
    float sum = 0.f, sq = 0.f;
    const float* xrow = x1 + (size_t)(rbase + l15) * DM;
    #pragma unroll
    for (int ks = 0; ks < 4; ks++) {
        float4 a = *(const float4*)(xrow + ks*32 + g16*8);
        float4 b = *(const float4*)(xrow + ks*32 + g16*8 + 4);
        xv[ks][0]=a.x; xv[ks][1]=a.y; xv[ks][2]=a.z; xv[ks][3]=a.w;
        xv[ks][4]=b.x; xv[ks][5]=b.y; xv[ks][6]=b.z; xv[ks][7]=b.w;
        sum += a.x+a.y+a.z+a.w + b.x+b.y+b.z+b.w;
        sq  += a.x*a.x+a.y*a.y+a.z*a.z+a.w*a.w + b.x*b.x+b.y*b.y+b.z*b.z+b.w*b.w;
    }
    sum += __shfl_xor(sum, 16); sum += __shfl_xor(sum, 32);
    sq  += __shfl_xor(sq, 16);  sq  += __shfl_xor(sq, 32);
    float mean = sum * (1.f/128.f);
    float var  = sq * (1.f/128.f) - mean * mean;
    float rstd = rsqrtf(var + 1e-5f);

    // ---- y = LN1(x) in f32 -> bf16 A-frags ----
    bf16x8 ah[4];
    #pragma unroll
    for (int ks = 0; ks < 4; ks++) {
        #pragma unroll
        for (int j = 0; j < 8; j++) {
            int col = ks*32 + g16*8 + j;
            float y = (xv[ks][j] - mean) * rstd * g1[col] + b1ln[col];
            ah[ks][j] = (bf16)y;
        }
    }

    // ---- GEMM1 + ReLU -> Hb, in two 8-tn chunks (acc = 32 VGPR) ----
    #pragma unroll
    for (int c = 0; c < 2; c++) {
        f32x4 h1[8];
        #pragma unroll
        for (int t = 0; t < 8; t++) h1[t] = {};
        #pragma unroll
        for (int ks = 0; ks < 4; ks++) {
            #pragma unroll
            for (int t = 0; t < 8; t++) {
                bf16x8 bh = *(const bf16x8*)(W1h + (size_t)(16*(8*c + t) + l15) * DM + ks*32 + g16*8);
                h1[t] = MFMA16(ah[ks], bh, h1[t]);
            }
        }
        #pragma unroll
        for (int t = 0; t < 8; t++) {
            int tn = 8*c + t;
            float bias = fb1[16*tn + l15];
            #pragma unroll
            for (int r = 0; r < 4; r++) {
                float v = fmaxf(h1[t][r] + bias, 0.f);
                myH[(4*g16 + r) * 264 + 16*tn + l15] = (bf16)v;
            }
        }
    }

    // ---- GEMM2 (plain bf16) ----
    f32x4 o[8];
    #pragma unroll
    for (int tn = 0; tn < 8; tn++) o[tn] = {};
    #pragma unroll
    for (int ks = 0; ks < 8; ks++) {
        bf16x8 a = *(const bf16x8*)(myH + l15 * 264 + ks*32 + g16*8);
        #pragma unroll
        for (int tn = 0; tn < 8; tn++) {
            bf16x8 bh = *(const bf16x8*)(W2h + (size_t)(16*tn + l15) * 256 + ks*32 + g16*8);
            o[tn] = MFMA16(a, bh, o[tn]);
        }
    }

    // ---- residual: recompute y for C-layout rows (exact f32), + LN2 ----
    #pragma unroll
    for (int r = 0; r < 4; r++) {
        int rw = 4*g16 + r;                       // row within wave tile
        int row = rbase + rw;
        float bm = __shfl(mean, rw);              // stats live in lanes 0..15
        float br = __shfl(rstd, rw);
        float tmp[8];
        float s2 = 0.f, q2 = 0.f;
        #pragma unroll
        for (int tn = 0; tn < 8; tn++) {
            int col = 16*tn + l15;
            float xr = x1[(size_t)row * DM + col];
            float y  = (xr - bm) * br * g1[col] + b1ln[col];
            float v  = o[tn][r] + fb2[col] + y;
            tmp[tn] = v; s2 += v; q2 += v * v;
        }
        #pragma unroll
        for (int d = 1; d <= 8; d <<= 1) { s2 += __shfl_xor(s2, d); q2 += __shfl_xor(q2, d); }
        float mean2 = s2 * (1.f/128.f);
        float var2  = q2 * (1.f/128.f) - mean2 * mean2;
        float rstd2 = rsqrtf(var2 + 1e-5f);
        #pragma unroll
        for (int tn = 0; tn < 8; tn++) {
            int col = 16*tn + l15;
            out[(size_t)row * DM + col] = (tmp[tn] - mean2) * rstd2 * g2[col] + b2ln[col];
        }
    }
}

// ---------------- launcher ----------------
extern "C" void kernel_launch(void* const* d_in, const int* in_sizes, int n_in,
                              void* d_out, int out_size, void* d_ws, size_t ws_size,
                              hipStream_t stream)
{
    const float* src      = (const float*)d_in[0];
    const float* src_prv  = (const float*)d_in[1];
    const float* pos      = (const float*)d_in[2];
    const float* pos_prv  = (const float*)d_in[3];
    const float* inpw     = (const float*)d_in[4];
    const float* inpb     = (const float*)d_in[5];
    const float* outpw    = (const float*)d_in[6];
    const float* outpb    = (const float*)d_in[7];
    const float* l1w      = (const float*)d_in[8];
    const float* l1b      = (const float*)d_in[9];
    const float* l2w      = (const float*)d_in[10];
    const float* l2b      = (const float*)d_in[11];
    const float* ln1g     = (const float*)d_in[12];
    const float* ln1b     = (const float*)d_in[13];
    const float* ln2g     = (const float*)d_in[14];
    const float* ln2b     = (const float*)d_in[15];
    const int* keep       = (const int*)d_in[16];
    const int* keep_p     = (const int*)d_in[17];
    const int* inds       = (const int*)d_in[18];
    const int* inds_p     = (const int*)d_in[19];
    const int n_inds = in_sizes[18], n_prv = in_sizes[19];

    char* wsb = (char*)d_ws;
    bf16* whi  = (bf16*)(wsb);                                  // 262144 B
    bf16* wlo  = (bf16*)(wsb + 262144);                         // 262144 B
    int*  mq   = (int*)(wsb + 524288);                          // 524288 B
    int*  mkv  = (int*)(wsb + 1048576);                         // 524288 B
    bf16* Qb   = (bf16*)(wsb + 1572864);                        // 33554432 B
    bf16* Kb   = (bf16*)(wsb + 1572864 + 33554432);             // 33554432 B
    bf16* Vtb  = (bf16*)(wsb + 1572864 + 2u*33554432);          // 33554432 B
    unsigned char* kmask = (unsigned char*)(wsb + 1572864 + 3u*33554432);  // 131072 B
    int* mflag = (int*)(wsb + 1572864 + 3u*33554432 + 131072);  // 4 B
    float* x1 = (float*)d_out;

    k_cvt_weights<<<512, 256, 0, stream>>>(inpw, outpw, l1w, l2w, whi, wlo);
    k_init_maps<<<512, 256, 0, stream>>>(mq, mkv, mflag);
    int mmax = n_inds > n_prv ? n_inds : n_prv;
    k_fill_maps<<<(mmax + 255) / 256, 256, 0, stream>>>(inds, keep, n_inds, inds_p, keep_p, n_prv, mq, mkv);
    k_mask_detect<<<128, 256, 0, stream>>>((const int*)d_in[20], mflag);
    k_mask_expand<<<512, 256, 0, stream>>>((const int*)d_in[20], (const unsigned char*)d_in[20], mflag, kmask);
    k_copy4<<<2048, 256, 0, stream>>>((const float4*)src, (float4*)x1, NTOT * DM / 4);
    k_qkv<<<NTOT / 64, 256, 0, stream>>>(src, src_prv, pos, pos_prv, whi, wlo, inpb, mq, mkv, Qb, Kb, Vtb);
    k_attn<<<NWIN, 256, 0, stream>>>(Qb, Kb, Vtb, whi, wlo, outpb, kmask, mq, x1);
    k_ffn<<<NTOT / 64, 256, 0, stream>>>(x1, whi, wlo, ln1g, ln1b, l1b, l2b, ln2g, ln2b, (float*)d_out);
}

// Round 9
// 533.663 us; speedup vs baseline: 1.3328x; 1.1027x over previous
//
#include <hip/hip_runtime.h>

#define NWIN 1024
#define WIN 128
#define DM 128
#define NTOT (NWIN*WIN)

typedef __bf16 bf16;
typedef __bf16 bf16x2 __attribute__((ext_vector_type(2)));
typedef __bf16 bf16x4 __attribute__((ext_vector_type(4)));
typedef __bf16 bf16x8 __attribute__((ext_vector_type(8)));
typedef float f32x4 __attribute__((ext_vector_type(4)));
typedef float f32x16 __attribute__((ext_vector_type(16)));

#define MFMA16(a,b,c) __builtin_amdgcn_mfma_f32_16x16x32_bf16(a,b,c,0,0,0)
#define MFMA32(a,b,c) __builtin_amdgcn_mfma_f32_32x32x16_bf16(a,b,c,0,0,0)

// ---------------- small prep kernels ----------------

__global__ void k_cvt_weights(const float* __restrict__ inproj, const float* __restrict__ outproj,
                              const float* __restrict__ w1, const float* __restrict__ w2,
                              bf16* __restrict__ whi, bf16* __restrict__ wlo) {
    int i = blockIdx.x * 256 + threadIdx.x;   // grid exactly 131072
    float v;
    if (i < 49152)       v = inproj[i];
    else if (i < 65536)  v = outproj[i - 49152];
    else if (i < 98304)  v = w1[i - 65536];
    else                 v = w2[i - 98304];
    bf16 h = (bf16)v;
    whi[i] = h;
    wlo[i] = (bf16)(v - (float)h);
}

__global__ void k_init_maps(int* __restrict__ mq, int* __restrict__ mkv, int* __restrict__ flag) {
    int i = blockIdx.x * 256 + threadIdx.x;
    if (i == 0) *flag = 0;
    if (i < NTOT) { mq[i] = -1; mkv[i] = -1; }
}

__global__ void k_fill_maps(const int* __restrict__ inds, const int* __restrict__ keep, int n,
                            const int* __restrict__ inds_p, const int* __restrict__ keep_p, int np,
                            int* __restrict__ mq, int* __restrict__ mkv) {
    int j = blockIdx.x * 256 + threadIdx.x;
    if (j < n)  mq[inds[j]]    = keep[j];
    if (j < np) mkv[inds_p[j]] = keep_p[j];
}

// Detect mask storage: if any int32 word of the mask is outside {0,1}, the bools
// are byte-packed (e.g. 0x01010101); else they are one int32 per element.
__global__ void k_mask_detect(const int* __restrict__ kpm_i, int* __restrict__ flag) {
    int i = blockIdx.x * 256 + threadIdx.x;   // grid 128 -> 32768 ints = 131072 bytes
    int v = kpm_i[i];
    if (v != 0 && v != 1) atomicOr(flag, 1);
}

__global__ void k_mask_expand(const int* __restrict__ kpm_i, const unsigned char* __restrict__ kpm_b,
                              const int* __restrict__ flag, unsigned char* __restrict__ kmask) {
    int i = blockIdx.x * 256 + threadIdx.x;   // grid 512 -> 131072
    int byte_mode = *flag;
    kmask[i] = byte_mode ? (kpm_b[i] != 0) : (kpm_i[i] != 0);
}

__global__ void k_copy4(const float4* __restrict__ s, float4* __restrict__ d, int n4) {
    int i = blockIdx.x * 256 + threadIdx.x;
    int stride = gridDim.x * 256;
    for (; i < n4; i += stride) d[i] = s[i];
}

// Plain-bf16 GEMM (one 16-row tile): acc += A @ W^T.
__device__ __forceinline__ void proj1p(const bf16* __restrict__ Xh,
                                       const bf16* __restrict__ WH,
                                       int l15, int g16, f32x4 acc[8]) {
    #pragma unroll
    for (int ks = 0; ks < 4; ks++) {
        bf16x8 ah = *(const bf16x8*)(Xh + l15 * 136 + ks*32 + g16*8);
        #pragma unroll
        for (int tn = 0; tn < 8; tn++) {
            bf16x8 bh = *(const bf16x8*)(WH + (size_t)(16*tn + l15) * DM + ks*32 + g16*8);
            acc[tn] = MFMA16(ah, bh, acc[tn]);
        }
    }
}

// ---------------- QKV projection (64-row panel per block), plain bf16 ----------------
// Q[w][tok][128], K[w][tok][128] row-major bf16; Vt[w][dim][key] transposed bf16.
// Static LDS = 35840 B: Xhi[64*136] + Bb[9216]  -> 4 blocks/CU.
__global__ __launch_bounds__(256, 4) void k_qkv(
    const float* __restrict__ src, const float* __restrict__ src_prv,
    const float* __restrict__ pos, const float* __restrict__ pos_prv,
    const bf16* __restrict__ whi,
    const float* __restrict__ bqkv,
    const int* __restrict__ mq, const int* __restrict__ mkv,
    bf16* __restrict__ Qg, bf16* __restrict__ Kg, bf16* __restrict__ Vtg)
{
    const int blk = blockIdx.x;            // 2048 blocks, 64 rows each
    const int rbase = blk * 64;
    const int w = blk >> 1;                // window index
    const int kb = (blk & 1) * 64;         // key offset within window
    const int tid = threadIdx.x;
    const int lane = tid & 63, wv = tid >> 6;
    const int l15 = lane & 15, g16 = lane >> 4;
    __shared__ bf16 Xhi[64*136];
    __shared__ bf16 Bb[9216];              // Q/K staging [64][136] or Vt staging [128][72]

    const int srow = tid >> 2, sq4 = tid & 3;   // 4 threads per row, 32 cols each

    // ---- stage x_q = gather(src) + pos ----
    {
        const int p = rbase + srow;
        const int g = mq[p];
        const float4* pr = (const float4*)(pos + (size_t)p * DM + sq4 * 32);
        const float4* sr = (g >= 0) ? (const float4*)(src + (size_t)g * DM + sq4 * 32) : nullptr;
        bf16* xh = Xhi + srow * 136 + sq4 * 32;
        #pragma unroll
        for (int i = 0; i < 8; i++) {
            float4 v = pr[i];
            if (sr) { float4 s4 = sr[i]; v.x += s4.x; v.y += s4.y; v.z += s4.z; v.w += s4.w; }
            bf16x4 h = { (bf16)v.x, (bf16)v.y, (bf16)v.z, (bf16)v.w };
            *(bf16x4*)(xh + i * 4) = h;
        }
    }
    __syncthreads();

    // ---- GEMM Q (wave wv owns rows 16*wv..+15) ----
    f32x4 qa[8];
    for (int tn = 0; tn < 8; tn++) qa[tn] = {};
    proj1p(Xhi + 16*wv*136, whi, l15, g16, qa);
    #pragma unroll
    for (int tn = 0; tn < 8; tn++) {
        float bias = bqkv[16*tn + l15];
        #pragma unroll
        for (int r = 0; r < 4; r++)
            Bb[(16*wv + 4*g16 + r) * 136 + 16*tn + l15] = (bf16)(qa[tn][r] + bias);
    }
    __syncthreads();   // X reads done; Bb(Q) written

    // ---- store Q from Bb; restage x_v = grid_prv (NO pos) ----
    {
        const int p = rbase + srow;
        const int g = mkv[p];
        bf16* xh = Xhi + srow * 136 + sq4 * 32;
        if (g >= 0) {
            const float4* sr = (const float4*)(src_prv + (size_t)g * DM + sq4 * 32);
            #pragma unroll
            for (int i = 0; i < 8; i++) {
                float4 v = sr[i];
                bf16x4 h = { (bf16)v.x, (bf16)v.y, (bf16)v.z, (bf16)v.w };
                *(bf16x4*)(xh + i * 4) = h;
            }
        } else {
            bf16x4 z = { (bf16)0.f, (bf16)0.f, (bf16)0.f, (bf16)0.f };
            #pragma unroll
            for (int i = 0; i < 8; i++) *(bf16x4*)(xh + i * 4) = z;
        }
    }
    #pragma unroll
    for (int it = 0; it < 4; it++) {
        int c = it * 256 + tid;
        int row = c >> 4, off = (c & 15) * 8;
        *(bf16x8*)(Qg + (size_t)(rbase + row) * DM + off) = *(const bf16x8*)(Bb + row*136 + off);
    }
    __syncthreads();   // x_v staged; Bb(Q) reads done

    // ---- GEMM V ----
    f32x4 va[8];
    for (int tn = 0; tn < 8; tn++) va[tn] = {};
    proj1p(Xhi + 16*wv*136, whi + 256*DM, l15, g16, va);
    #pragma unroll
    for (int tn = 0; tn < 8; tn++) {
        float bias = bqkv[256 + 16*tn + l15];
        int dim = 16*tn + l15;
        bf16x4 b = { (bf16)(va[tn][0] + bias), (bf16)(va[tn][1] + bias),
                     (bf16)(va[tn][2] + bias), (bf16)(va[tn][3] + bias) };
        *(bf16x4*)(Bb + dim * 72 + 16*wv + 4*g16) = b;   // Vt staging [128][72]
    }
    __syncthreads();   // X reads done; Bb(Vt) written

    // ---- store Vt from Bb; X += pos_prv in place ----
    {
        const int p = rbase + srow;
        const float4* pr = (const float4*)(pos_prv + (size_t)p * DM + sq4 * 32);
        bf16* xh = Xhi + srow * 136 + sq4 * 32;
        #pragma unroll
        for (int i = 0; i < 8; i++) {
            float4 v = pr[i];
            bf16x4 ch = *(const bf16x4*)(xh + i * 4);
            bf16x4 h = { (bf16)((float)ch.x + v.x), (bf16)((float)ch.y + v.y),
                         (bf16)((float)ch.z + v.z), (bf16)((float)ch.w + v.w) };
            *(bf16x4*)(xh + i * 4) = h;
        }
    }
    #pragma unroll
    for (int it = 0; it < 4; it++) {
        int c = it * 256 + tid;
        int dim = c >> 3, off = (c & 7) * 8;
        *(bf16x8*)(Vtg + ((size_t)w * 128 + dim) * 128 + kb + off) = *(const bf16x8*)(Bb + dim*72 + off);
    }
    __syncthreads();   // x_k staged; Bb(Vt) reads done

    // ---- GEMM K ----
    f32x4 ka[8];
    for (int tn = 0; tn < 8; tn++) ka[tn] = {};
    proj1p(Xhi + 16*wv*136, whi + 128*DM, l15, g16, ka);
    #pragma unroll
    for (int tn = 0; tn < 8; tn++) {
        float bias = bqkv[128 + 16*tn + l15];
        #pragma unroll
        for (int r = 0; r < 4; r++)
            Bb[(16*wv + 4*g16 + r) * 136 + 16*tn + l15] = (bf16)(ka[tn][r] + bias);
    }
    __syncthreads();
    #pragma unroll
    for (int it = 0; it < 4; it++) {
        int c = it * 256 + tid;
        int row = c >> 4, off = (c & 15) * 8;
        *(bf16x8*)(Kg + (size_t)(rbase + row) * DM + off) = *(const bf16x8*)(Bb + row*136 + off);
    }
}

// ---------------- attention + out_proj + scatter-add (per window) ----------------
__global__ __launch_bounds__(256) void k_attn(
    const bf16* __restrict__ Qg, const bf16* __restrict__ Kg, const bf16* __restrict__ Vtg,
    const bf16* __restrict__ whi, const bf16* __restrict__ wlo, const float* __restrict__ ob,
    const unsigned char* __restrict__ kmask, const int* __restrict__ mq,
    float* __restrict__ x1)
{
    const int w = blockIdx.x;
    const int tid = threadIdx.x;
    const int lane = tid & 63, wv = tid >> 6;
    const int l15 = lane & 15, g16 = lane >> 4;
    const int l31 = lane & 31, h32 = lane >> 5;
    __shared__ bf16 P[4][32 * 136];
    bf16* myP = &P[wv][0];

    bool msk[4];
    #pragma unroll
    for (int kt = 0; kt < 4; kt++) msk[kt] = kmask[w * WIN + 32*kt + l31] != 0;

    const bf16* Qw = Qg + (size_t)w * WIN * DM;
    const bf16* Kw = Kg + (size_t)w * WIN * DM;
    const bf16* Vw = Vtg + (size_t)w * WIN * DM;

    f32x4 oacc[8][2];
    for (int h = 0; h < 8; h++) { oacc[h][0] = {}; oacc[h][1] = {}; }

    #pragma unroll
    for (int h = 0; h < 8; h++) {
        // S = Q_h @ K_h^T  (32 query rows per wave, 4 key tiles, K=16 per MFMA)
        bf16x8 qf = *(const bf16x8*)(Qw + (size_t)(32*wv + l31) * DM + 16*h + h32*8);
        f32x16 s[4];
        #pragma unroll
        for (int kt = 0; kt < 4; kt++) {
            bf16x8 kf = *(const bf16x8*)(Kw + (size_t)(32*kt + l31) * DM + 16*h + h32*8);
            f32x16 z = {};
            s[kt] = MFMA32(qf, kf, z);
        }
        #pragma unroll
        for (int kt = 0; kt < 4; kt++) {
            #pragma unroll
            for (int r = 0; r < 16; r++)
                s[kt][r] = msk[kt] ? -1e9f : s[kt][r] * 0.25f;
        }
        // row softmax (row = (r&3)+8*(r>>2)+4*h32, cols across 32 lanes x 4 tiles)
        #pragma unroll
        for (int r = 0; r < 16; r++) {
            float m = fmaxf(fmaxf(s[0][r], s[1][r]), fmaxf(s[2][r], s[3][r]));
            #pragma unroll
            for (int d = 1; d <= 16; d <<= 1) m = fmaxf(m, __shfl_xor(m, d));
            float e0 = __expf(s[0][r] - m), e1 = __expf(s[1][r] - m);
            float e2 = __expf(s[2][r] - m), e3 = __expf(s[3][r] - m);
            float sum = e0 + e1 + e2 + e3;
            #pragma unroll
            for (int d = 1; d <= 16; d <<= 1) sum += __shfl_xor(sum, d);
            float inv = __builtin_amdgcn_rcpf(sum);
            int qrow = (r & 3) + 8 * (r >> 2) + 4 * h32;
            myP[qrow * 136 +      l31] = (bf16)(e0 * inv);
            myP[qrow * 136 + 32 + l31] = (bf16)(e1 * inv);
            myP[qrow * 136 + 64 + l31] = (bf16)(e2 * inv);
            myP[qrow * 136 + 96 + l31] = (bf16)(e3 * inv);
        }
        // O_h += P @ V_h   (B-operand = Vt rows, 8 contiguous keys)
        #pragma unroll
        for (int ks = 0; ks < 4; ks++) {
            bf16x8 p0 = *(const bf16x8*)(myP + (l15     ) * 136 + ks*32 + g16*8);
            bf16x8 p1 = *(const bf16x8*)(myP + (16 + l15) * 136 + ks*32 + g16*8);
            bf16x8 vf = *(const bf16x8*)(Vw + (size_t)(16*h + l15) * DM + ks*32 + g16*8);
            oacc[h][0] = MFMA16(p0, vf, oacc[h][0]);
            oacc[h][1] = MFMA16(p1, vf, oacc[h][1]);
        }
    }

    // O -> LDS (reuse P region), then out_proj (2-term: Wo hi + lo)
    #pragma unroll
    for (int h = 0; h < 8; h++) {
        #pragma unroll
        for (int tq = 0; tq < 2; tq++) {
            #pragma unroll
            for (int r = 0; r < 4; r++)
                myP[(16*tq + 4*g16 + r) * 136 + 16*h + l15] = (bf16)oacc[h][tq][r];
        }
    }

    const bf16* Woh = whi + 49152;
    const bf16* Wol = wlo + 49152;
    f32x4 oc[2][8];
    for (int tq = 0; tq < 2; tq++)
        for (int tn = 0; tn < 8; tn++)
            oc[tq][tn] = {};
    #pragma unroll
    for (int ks = 0; ks < 4; ks++) {
        bf16x8 a0 = *(const bf16x8*)(myP + (l15     ) * 136 + ks*32 + g16*8);
        bf16x8 a1 = *(const bf16x8*)(myP + (16 + l15) * 136 + ks*32 + g16*8);
        #pragma unroll
        for (int tn = 0; tn < 8; tn++) {
            bf16x8 bh = *(const bf16x8*)(Woh + (size_t)(16*tn + l15) * DM + ks*32 + g16*8);
            bf16x8 bl = *(const bf16x8*)(Wol + (size_t)(16*tn + l15) * DM + ks*32 + g16*8);
            oc[0][tn] = MFMA16(a0, bh, oc[0][tn]);
            oc[0][tn] = MFMA16(a0, bl, oc[0][tn]);
            oc[1][tn] = MFMA16(a1, bh, oc[1][tn]);
            oc[1][tn] = MFMA16(a1, bl, oc[1][tn]);
        }
    }

    float obv[8];
    #pragma unroll
    for (int tn = 0; tn < 8; tn++) obv[tn] = ob[16*tn + l15];
    #pragma unroll
    for (int tq = 0; tq < 2; tq++) {
        #pragma unroll
        for (int r = 0; r < 4; r++) {
            int qrow = 32*wv + 16*tq + 4*g16 + r;
            int g = mq[w * WIN + qrow];
            if (g < 0) continue;
            float* orow = x1 + (size_t)g * DM;
            #pragma unroll
            for (int tn = 0; tn < 8; tn++)
                orow[16*tn + l15] += oc[tq][tn][r] + obv[tn];
        }
    }
}

// ---------------- fused LN1 + FFN + residual + LN2 (64 rows/block, 16 rows/wave) ----------------
__global__ __launch_bounds__(256, 4) void k_ffn(
    const float* __restrict__ x1, const bf16* __restrict__ whi, const bf16* __restrict__ wlo,
    const float* __restrict__ g1, const float* __restrict__ b1ln,
    const float* __restrict__ fb1, const float* __restrict__ fb2,
    const float* __restrict__ g2, const float* __restrict__ b2ln,
    float* __restrict__ out)
{
    const int tid = threadIdx.x;
    const int lane = tid & 63, wv = tid >> 6;
    const int l15 = lane & 15, g16 = lane >> 4;
    const int rbase = blockIdx.x * 64 + wv * 16;
    __shared__ bf16 Hb[4][16 * 264];
    bf16* myH = &Hb[wv][0];
    const bf16* W1h = whi + 65536;
    const bf16* W2h = whi + 98304;

    // ---- LN1 stats: lane owns row rbase+l15, 32 of its cols ----
    float xv[4][8];
    float sum = 0.f, sq = 0.f;
    const float* xrow = x1 + (size_t)(rbase + l15) * DM;
    #pragma unroll
    for (int ks = 0; ks < 4; ks++) {
        float4 a = *(const float4*)(xrow + ks*32 + g16*8);
        float4 b = *(const float4*)(xrow + ks*32 + g16*8 + 4);
        xv[ks][0]=a.x; xv[ks][1]=a.y; xv[ks][2]=a.z; xv[ks][3]=a.w;
        xv[ks][4]=b.x; xv[ks][5]=b.y; xv[ks][6]=b.z; xv[ks][7]=b.w;
        sum += a.x+a.y+a.z+a.w + b.x+b.y+b.z+b.w;
        sq  += a.x*a.x+a.y*a.y+a.z*a.z+a.w*a.w + b.x*b.x+b.y*b.y+b.z*b.z+b.w*b.w;
    }
    sum += __shfl_xor(sum, 16); sum += __shfl_xor(sum, 32);
    sq  += __shfl_xor(sq, 16);  sq  += __shfl_xor(sq, 32);
    float mean = sum * (1.f/128.f);
    float var  = sq * (1.f/128.f) - mean * mean;
    float rstd = rsqrtf(var + 1e-5f);

    // ---- y = LN1(x) in f32 -> bf16 A-frags ----
    bf16x8 ah[4];
    #pragma unroll
    for (int ks = 0; ks < 4; ks++) {
        #pragma unroll
        for (int j = 0; j < 8; j++) {
            int col = ks*32 + g16*8 + j;
            float y = (xv[ks][j] - mean) * rstd * g1[col] + b1ln[col];
            ah[ks][j] = (bf16)y;
        }
    }

    // ---- GEMM1 + ReLU -> Hb, in two 8-tn chunks (acc = 32 VGPR) ----
    #pragma unroll
    for (int c = 0; c < 2; c++) {
        f32x4 h1[8];
        #pragma unroll
        for (int t = 0; t < 8; t++) h1[t] = {};
        #pragma unroll
        for (int ks = 0; ks < 4; ks++) {
            #pragma unroll
            for (int t = 0; t < 8; t++) {
                bf16x8 bh = *(const bf16x8*)(W1h + (size_t)(16*(8*c + t) + l15) * DM + ks*32 + g16*8);
                h1[t] = MFMA16(ah[ks], bh, h1[t]);
            }
        }
        #pragma unroll
        for (int t = 0; t < 8; t++) {
            int tn = 8*c + t;
            float bias = fb1[16*tn + l15];
            #pragma unroll
            for (int r = 0; r < 4; r++) {
                float v = fmaxf(h1[t][r] + bias, 0.f);
                myH[(4*g16 + r) * 264 + 16*tn + l15] = (bf16)v;
            }
        }
    }

    // ---- GEMM2 (plain bf16) ----
    f32x4 o[8];
    #pragma unroll
    for (int tn = 0; tn < 8; tn++) o[tn] = {};
    #pragma unroll
    for (int ks = 0; ks < 8; ks++) {
        bf16x8 a = *(const bf16x8*)(myH + l15 * 264 + ks*32 + g16*8);
        #pragma unroll
        for (int tn = 0; tn < 8; tn++) {
            bf16x8 bh = *(const bf16x8*)(W2h + (size_t)(16*tn + l15) * 256 + ks*32 + g16*8);
            o[tn] = MFMA16(a, bh, o[tn]);
        }
    }

    // ---- residual: recompute y for C-layout rows (exact f32), + LN2 ----
    #pragma unroll
    for (int r = 0; r < 4; r++) {
        int rw = 4*g16 + r;                       // row within wave tile
        int row = rbase + rw;
        float bm = __shfl(mean, rw);              // stats live in lanes 0..15
        float br = __shfl(rstd, rw);
        float tmp[8];
        float s2 = 0.f, q2 = 0.f;
        #pragma unroll
        for (int tn = 0; tn < 8; tn++) {
            int col = 16*tn + l15;
            float xr = x1[(size_t)row * DM + col];
            float y  = (xr - bm) * br * g1[col] + b1ln[col];
            float v  = o[tn][r] + fb2[col] + y;
            tmp[tn] = v; s2 += v; q2 += v * v;
        }
        #pragma unroll
        for (int d = 1; d <= 8; d <<= 1) { s2 += __shfl_xor(s2, d); q2 += __shfl_xor(q2, d); }
        float mean2 = s2 * (1.f/128.f);
        float var2  = q2 * (1.f/128.f) - mean2 * mean2;
        float rstd2 = rsqrtf(var2 + 1e-5f);
        #pragma unroll
        for (int tn = 0; tn < 8; tn++) {
            int col = 16*tn + l15;
            out[(size_t)row * DM + col] = (tmp[tn] - mean2) * rstd2 * g2[col] + b2ln[col];
        }
    }
}

// ---------------- launcher ----------------
extern "C" void kernel_launch(void* const* d_in, const int* in_sizes, int n_in,
                              void* d_out, int out_size, void* d_ws, size_t ws_size,
                              hipStream_t stream)
{
    const float* src      = (const float*)d_in[0];
    const float* src_prv  = (const float*)d_in[1];
    const float* pos      = (const float*)d_in[2];
    const float* pos_prv  = (const float*)d_in[3];
    const float* inpw     = (const float*)d_in[4];
    const float* inpb     = (const float*)d_in[5];
    const float* outpw    = (const float*)d_in[6];
    const float* outpb    = (const float*)d_in[7];
    const float* l1w      = (const float*)d_in[8];
    const float* l1b      = (const float*)d_in[9];
    const float* l2w      = (const float*)d_in[10];
    const float* l2b      = (const float*)d_in[11];
    const float* ln1g     = (const float*)d_in[12];
    const float* ln1b     = (const float*)d_in[13];
    const float* ln2g     = (const float*)d_in[14];
    const float* ln2b     = (const float*)d_in[15];
    const int* keep       = (const int*)d_in[16];
    const int* keep_p     = (const int*)d_in[17];
    const int* inds       = (const int*)d_in[18];
    const int* inds_p     = (const int*)d_in[19];
    const int n_inds = in_sizes[18], n_prv = in_sizes[19];

    char* wsb = (char*)d_ws;
    bf16* whi  = (bf16*)(wsb);                                  // 262144 B
    bf16* wlo  = (bf16*)(wsb + 262144);                         // 262144 B
    int*  mq   = (int*)(wsb + 524288);                          // 524288 B
    int*  mkv  = (int*)(wsb + 1048576);                         // 524288 B
    bf16* Qb   = (bf16*)(wsb + 1572864);                        // 33554432 B
    bf16* Kb   = (bf16*)(wsb + 1572864 + 33554432);             // 33554432 B
    bf16* Vtb  = (bf16*)(wsb + 1572864 + 2u*33554432);          // 33554432 B
    unsigned char* kmask = (unsigned char*)(wsb + 1572864 + 3u*33554432);  // 131072 B
    int* mflag = (int*)(wsb + 1572864 + 3u*33554432 + 131072);  // 4 B
    float* x1 = (float*)d_out;

    k_cvt_weights<<<512, 256, 0, stream>>>(inpw, outpw, l1w, l2w, whi, wlo);
    k_init_maps<<<512, 256, 0, stream>>>(mq, mkv, mflag);
    int mmax = n_inds > n_prv ? n_inds : n_prv;
    k_fill_maps<<<(mmax + 255) / 256, 256, 0, stream>>>(inds, keep, n_inds, inds_p, keep_p, n_prv, mq, mkv);
    k_mask_detect<<<128, 256, 0, stream>>>((const int*)d_in[20], mflag);
    k_mask_expand<<<512, 256, 0, stream>>>((const int*)d_in[20], (const unsigned char*)d_in[20], mflag, kmask);
    k_copy4<<<2048, 256, 0, stream>>>((const float4*)src, (float4*)x1, NTOT * DM / 4);
    k_qkv<<<NTOT / 64, 256, 0, stream>>>(src, src_prv, pos, pos_prv, whi, inpb, mq, mkv, Qb, Kb, Vtb);
    k_attn<<<NWIN, 256, 0, stream>>>(Qb, Kb, Vtb, whi, wlo, outpb, kmask, mq, x1);
    k_ffn<<<NTOT / 64, 256, 0, stream>>>(x1, whi, wlo, ln1g, ln1b, l1b, l2b, ln2g, ln2b, (float*)d_out);
}

// Round 10
// 477.320 us; speedup vs baseline: 1.4901x; 1.1180x over previous
//
#include <hip/hip_runtime.h>

#define NWIN 1024
#define WIN 128
#define DM 128
#define NTOT (NWIN*WIN)

typedef __bf16 bf16;
typedef __bf16 bf16x2 __attribute__((ext_vector_type(2)));
typedef __bf16 bf16x4 __attribute__((ext_vector_type(4)));
typedef __bf16 bf16x8 __attribute__((ext_vector_type(8)));
typedef float f32x4 __attribute__((ext_vector_type(4)));
typedef float f32x16 __attribute__((ext_vector_type(16)));

#define MFMA16(a,b,c) __builtin_amdgcn_mfma_f32_16x16x32_bf16(a,b,c,0,0,0)
#define MFMA32(a,b,c) __builtin_amdgcn_mfma_f32_32x32x16_bf16(a,b,c,0,0,0)

// ---------------- prep kernels (merged: 3 launches) ----------------

// grid 512: weights->bf16 hi/lo (131072), maps init (131072 == NTOT), flag=0
__global__ void k_prep1(const float* __restrict__ inproj, const float* __restrict__ outproj,
                        const float* __restrict__ w1, const float* __restrict__ w2,
                        bf16* __restrict__ whi, bf16* __restrict__ wlo,
                        int* __restrict__ mq, int* __restrict__ mkv, int* __restrict__ flag) {
    int i = blockIdx.x * 256 + threadIdx.x;
    if (i == 0) *flag = 0;
    float v;
    if (i < 49152)       v = inproj[i];
    else if (i < 65536)  v = outproj[i - 49152];
    else if (i < 98304)  v = w1[i - 65536];
    else                 v = w2[i - 98304];
    bf16 h = (bf16)v;
    whi[i] = h;
    wlo[i] = (bf16)(v - (float)h);
    mq[i] = -1; mkv[i] = -1;
}

// grid covers max(n_inds, n_prv, 32768): mask-mode detect + scatter-map fill
__global__ void k_prep2(const int* __restrict__ kpm_i, int* __restrict__ flag,
                        const int* __restrict__ inds, const int* __restrict__ keep, int n,
                        const int* __restrict__ inds_p, const int* __restrict__ keep_p, int np,
                        int* __restrict__ mq, int* __restrict__ mkv) {
    int j = blockIdx.x * 256 + threadIdx.x;
    if (j < 32768) {                      // first 131072 bytes as ints
        int v = kpm_i[j];
        if (v != 0 && v != 1) atomicOr(flag, 1);
    }
    if (j < n)  mq[inds[j]]    = keep[j];
    if (j < np) mkv[inds_p[j]] = keep_p[j];
}

// grid 2048: mask expand (131072) + src->x1 copy (grid-stride float4)
__global__ void k_prep3(const int* __restrict__ kpm_i, const unsigned char* __restrict__ kpm_b,
                        const int* __restrict__ flag, unsigned char* __restrict__ kmask,
                        const float4* __restrict__ s, float4* __restrict__ d, int n4) {
    int i = blockIdx.x * 256 + threadIdx.x;
    if (i < 131072) {
        int byte_mode = *flag;
        kmask[i] = byte_mode ? (kpm_b[i] != 0) : (kpm_i[i] != 0);
    }
    int stride = gridDim.x * 256;
    for (int k = i; k < n4; k += stride) d[k] = s[k];
}

// Plain-bf16 GEMM (one 16-row tile): acc += A @ W^T.
__device__ __forceinline__ void proj1p(const bf16* __restrict__ Xh,
                                       const bf16* __restrict__ WH,
                                       int l15, int g16, f32x4 acc[8]) {
    #pragma unroll
    for (int ks = 0; ks < 4; ks++) {
        bf16x8 ah = *(const bf16x8*)(Xh + l15 * 136 + ks*32 + g16*8);
        #pragma unroll
        for (int tn = 0; tn < 8; tn++) {
            bf16x8 bh = *(const bf16x8*)(WH + (size_t)(16*tn + l15) * DM + ks*32 + g16*8);
            acc[tn] = MFMA16(ah, bh, acc[tn]);
        }
    }
}

// ---------------- QKV projection (64-row panel per block), plain bf16 ----------------
// T14 async-stage: x_v gather issued at kernel top (hidden under stage+GEMM Q);
// pos_prv issued after GEMM Q (hidden under Q-store + GEMM V).
__global__ __launch_bounds__(256, 4) void k_qkv(
    const float* __restrict__ src, const float* __restrict__ src_prv,
    const float* __restrict__ pos, const float* __restrict__ pos_prv,
    const bf16* __restrict__ whi,
    const float* __restrict__ bqkv,
    const int* __restrict__ mq, const int* __restrict__ mkv,
    bf16* __restrict__ Qg, bf16* __restrict__ Kg, bf16* __restrict__ Vtg)
{
    const int blk = blockIdx.x;            // 2048 blocks, 64 rows each
    const int rbase = blk * 64;
    const int w = blk >> 1;                // window index
    const int kb = (blk & 1) * 64;         // key offset within window
    const int tid = threadIdx.x;
    const int lane = tid & 63, wv = tid >> 6;
    const int l15 = lane & 15, g16 = lane >> 4;
    __shared__ bf16 Xhi[64*136];
    __shared__ bf16 Bb[9216];              // Q/K staging [64][136] or Vt staging [128][72]

    const int srow = tid >> 2, sq4 = tid & 3;   // 4 threads per row, 32 cols each
    const int p = rbase + srow;
    const int gq = mq[p];
    const int gv = mkv[p];

    // ---- issue x_q loads AND prefetch x_v gather (regs) ----
    float4 aq[8], bq[8], vv[8];
    {
        const float4* pr = (const float4*)(pos + (size_t)p * DM + sq4 * 32);
        #pragma unroll
        for (int i = 0; i < 8; i++) aq[i] = pr[i];
        if (gq >= 0) {
            const float4* sr = (const float4*)(src + (size_t)gq * DM + sq4 * 32);
            #pragma unroll
            for (int i = 0; i < 8; i++) bq[i] = sr[i];
        }
        if (gv >= 0) {
            const float4* vr = (const float4*)(src_prv + (size_t)gv * DM + sq4 * 32);
            #pragma unroll
            for (int i = 0; i < 8; i++) vv[i] = vr[i];
        }
        bf16* xh = Xhi + srow * 136 + sq4 * 32;
        #pragma unroll
        for (int i = 0; i < 8; i++) {
            float4 v = aq[i];
            if (gq >= 0) { v.x += bq[i].x; v.y += bq[i].y; v.z += bq[i].z; v.w += bq[i].w; }
            bf16x4 h = { (bf16)v.x, (bf16)v.y, (bf16)v.z, (bf16)v.w };
            *(bf16x4*)(xh + i * 4) = h;
        }
    }
    __syncthreads();

    // ---- GEMM Q (wave wv owns rows 16*wv..+15) ----
    f32x4 qa[8];
    for (int tn = 0; tn < 8; tn++) qa[tn] = {};
    proj1p(Xhi + 16*wv*136, whi, l15, g16, qa);
    #pragma unroll
    for (int tn = 0; tn < 8; tn++) {
        float bias = bqkv[16*tn + l15];
        #pragma unroll
        for (int r = 0; r < 4; r++)
            Bb[(16*wv + 4*g16 + r) * 136 + 16*tn + l15] = (bf16)(qa[tn][r] + bias);
    }
    // ---- prefetch pos_prv (regs), hidden under Q-store + GEMM V ----
    float4 pp[8];
    {
        const float4* ppr = (const float4*)(pos_prv + (size_t)p * DM + sq4 * 32);
        #pragma unroll
        for (int i = 0; i < 8; i++) pp[i] = ppr[i];
    }
    __syncthreads();   // X reads done; Bb(Q) written

    // ---- write x_v (prefetched) to X; store Q from Bb ----
    {
        bf16* xh = Xhi + srow * 136 + sq4 * 32;
        if (gv >= 0) {
            #pragma unroll
            for (int i = 0; i < 8; i++) {
                bf16x4 h = { (bf16)vv[i].x, (bf16)vv[i].y, (bf16)vv[i].z, (bf16)vv[i].w };
                *(bf16x4*)(xh + i * 4) = h;
            }
        } else {
            bf16x4 z = { (bf16)0.f, (bf16)0.f, (bf16)0.f, (bf16)0.f };
            #pragma unroll
            for (int i = 0; i < 8; i++) *(bf16x4*)(xh + i * 4) = z;
        }
    }
    #pragma unroll
    for (int it = 0; it < 4; it++) {
        int c = it * 256 + tid;
        int row = c >> 4, off = (c & 15) * 8;
        *(bf16x8*)(Qg + (size_t)(rbase + row) * DM + off) = *(const bf16x8*)(Bb + row*136 + off);
    }
    __syncthreads();   // x_v staged; Bb(Q) reads done

    // ---- GEMM V ----
    f32x4 va[8];
    for (int tn = 0; tn < 8; tn++) va[tn] = {};
    proj1p(Xhi + 16*wv*136, whi + 256*DM, l15, g16, va);
    #pragma unroll
    for (int tn = 0; tn < 8; tn++) {
        float bias = bqkv[256 + 16*tn + l15];
        int dim = 16*tn + l15;
        bf16x4 b = { (bf16)(va[tn][0] + bias), (bf16)(va[tn][1] + bias),
                     (bf16)(va[tn][2] + bias), (bf16)(va[tn][3] + bias) };
        *(bf16x4*)(Bb + dim * 72 + 16*wv + 4*g16) = b;   // Vt staging [128][72]
    }
    __syncthreads();   // X reads done; Bb(Vt) written

    // ---- X += pos_prv (prefetched regs); store Vt from Bb ----
    {
        bf16* xh = Xhi + srow * 136 + sq4 * 32;
        #pragma unroll
        for (int i = 0; i < 8; i++) {
            bf16x4 ch = *(const bf16x4*)(xh + i * 4);
            bf16x4 h = { (bf16)((float)ch.x + pp[i].x), (bf16)((float)ch.y + pp[i].y),
                         (bf16)((float)ch.z + pp[i].z), (bf16)((float)ch.w + pp[i].w) };
            *(bf16x4*)(xh + i * 4) = h;
        }
    }
    #pragma unroll
    for (int it = 0; it < 4; it++) {
        int c = it * 256 + tid;
        int dim = c >> 3, off = (c & 7) * 8;
        *(bf16x8*)(Vtg + ((size_t)w * 128 + dim) * 128 + kb + off) = *(const bf16x8*)(Bb + dim*72 + off);
    }
    __syncthreads();   // x_k staged; Bb(Vt) reads done

    // ---- GEMM K ----
    f32x4 ka[8];
    for (int tn = 0; tn < 8; tn++) ka[tn] = {};
    proj1p(Xhi + 16*wv*136, whi + 128*DM, l15, g16, ka);
    #pragma unroll
    for (int tn = 0; tn < 8; tn++) {
        float bias = bqkv[128 + 16*tn + l15];
        #pragma unroll
        for (int r = 0; r < 4; r++)
            Bb[(16*wv + 4*g16 + r) * 136 + 16*tn + l15] = (bf16)(ka[tn][r] + bias);
    }
    __syncthreads();
    #pragma unroll
    for (int it = 0; it < 4; it++) {
        int c = it * 256 + tid;
        int row = c >> 4, off = (c & 15) * 8;
        *(bf16x8*)(Kg + (size_t)(rbase + row) * DM + off) = *(const bf16x8*)(Bb + row*136 + off);
    }
}

// ---------------- attention + out_proj + scatter-add (per window) ----------------
__global__ __launch_bounds__(256) void k_attn(
    const bf16* __restrict__ Qg, const bf16* __restrict__ Kg, const bf16* __restrict__ Vtg,
    const bf16* __restrict__ whi, const bf16* __restrict__ wlo, const float* __restrict__ ob,
    const unsigned char* __restrict__ kmask, const int* __restrict__ mq,
    float* __restrict__ x1)
{
    const int w = blockIdx.x;
    const int tid = threadIdx.x;
    const int lane = tid & 63, wv = tid >> 6;
    const int l15 = lane & 15, g16 = lane >> 4;
    const int l31 = lane & 31, h32 = lane >> 5;
    __shared__ bf16 P[4][32 * 136];
    bf16* myP = &P[wv][0];

    bool msk[4];
    #pragma unroll
    for (int kt = 0; kt < 4; kt++) msk[kt] = kmask[w * WIN + 32*kt + l31] != 0;

    const bf16* Qw = Qg + (size_t)w * WIN * DM;
    const bf16* Kw = Kg + (size_t)w * WIN * DM;
    const bf16* Vw = Vtg + (size_t)w * WIN * DM;

    f32x4 oacc[8][2];
    for (int h = 0; h < 8; h++) { oacc[h][0] = {}; oacc[h][1] = {}; }

    #pragma unroll
    for (int h = 0; h < 8; h++) {
        // S = Q_h @ K_h^T  (32 query rows per wave, 4 key tiles, K=16 per MFMA)
        bf16x8 qf = *(const bf16x8*)(Qw + (size_t)(32*wv + l31) * DM + 16*h + h32*8);
        f32x16 s[4];
        #pragma unroll
        for (int kt = 0; kt < 4; kt++) {
            bf16x8 kf = *(const bf16x8*)(Kw + (size_t)(32*kt + l31) * DM + 16*h + h32*8);
            f32x16 z = {};
            s[kt] = MFMA32(qf, kf, z);
        }
        #pragma unroll
        for (int kt = 0; kt < 4; kt++) {
            #pragma unroll
            for (int r = 0; r < 16; r++)
                s[kt][r] = msk[kt] ? -1e9f : s[kt][r] * 0.25f;
        }
        // row softmax (row = (r&3)+8*(r>>2)+4*h32, cols across 32 lanes x 4 tiles)
        #pragma unroll
        for (int r = 0; r < 16; r++) {
            float m = fmaxf(fmaxf(s[0][r], s[1][r]), fmaxf(s[2][r], s[3][r]));
            #pragma unroll
            for (int d = 1; d <= 16; d <<= 1) m = fmaxf(m, __shfl_xor(m, d));
            float e0 = __expf(s[0][r] - m), e1 = __expf(s[1][r] - m);
            float e2 = __expf(s[2][r] - m), e3 = __expf(s[3][r] - m);
            float sum = e0 + e1 + e2 + e3;
            #pragma unroll
            for (int d = 1; d <= 16; d <<= 1) sum += __shfl_xor(sum, d);
            float inv = __builtin_amdgcn_rcpf(sum);
            int qrow = (r & 3) + 8 * (r >> 2) + 4 * h32;
            myP[qrow * 136 +      l31] = (bf16)(e0 * inv);
            myP[qrow * 136 + 32 + l31] = (bf16)(e1 * inv);
            myP[qrow * 136 + 64 + l31] = (bf16)(e2 * inv);
            myP[qrow * 136 + 96 + l31] = (bf16)(e3 * inv);
        }
        // O_h += P @ V_h   (B-operand = Vt rows, 8 contiguous keys)
        #pragma unroll
        for (int ks = 0; ks < 4; ks++) {
            bf16x8 p0 = *(const bf16x8*)(myP + (l15     ) * 136 + ks*32 + g16*8);
            bf16x8 p1 = *(const bf16x8*)(myP + (16 + l15) * 136 + ks*32 + g16*8);
            bf16x8 vf = *(const bf16x8*)(Vw + (size_t)(16*h + l15) * DM + ks*32 + g16*8);
            oacc[h][0] = MFMA16(p0, vf, oacc[h][0]);
            oacc[h][1] = MFMA16(p1, vf, oacc[h][1]);
        }
    }

    // O -> LDS (reuse P region), then out_proj (2-term: Wo hi + lo)
    #pragma unroll
    for (int h = 0; h < 8; h++) {
        #pragma unroll
        for (int tq = 0; tq < 2; tq++) {
            #pragma unroll
            for (int r = 0; r < 4; r++)
                myP[(16*tq + 4*g16 + r) * 136 + 16*h + l15] = (bf16)oacc[h][tq][r];
        }
    }

    const bf16* Woh = whi + 49152;
    const bf16* Wol = wlo + 49152;
    f32x4 oc[2][8];
    for (int tq = 0; tq < 2; tq++)
        for (int tn = 0; tn < 8; tn++)
            oc[tq][tn] = {};
    #pragma unroll
    for (int ks = 0; ks < 4; ks++) {
        bf16x8 a0 = *(const bf16x8*)(myP + (l15     ) * 136 + ks*32 + g16*8);
        bf16x8 a1 = *(const bf16x8*)(myP + (16 + l15) * 136 + ks*32 + g16*8);
        #pragma unroll
        for (int tn = 0; tn < 8; tn++) {
            bf16x8 bh = *(const bf16x8*)(Woh + (size_t)(16*tn + l15) * DM + ks*32 + g16*8);
            bf16x8 bl = *(const bf16x8*)(Wol + (size_t)(16*tn + l15) * DM + ks*32 + g16*8);
            oc[0][tn] = MFMA16(a0, bh, oc[0][tn]);
            oc[0][tn] = MFMA16(a0, bl, oc[0][tn]);
            oc[1][tn] = MFMA16(a1, bh, oc[1][tn]);
            oc[1][tn] = MFMA16(a1, bl, oc[1][tn]);
        }
    }

    float obv[8];
    #pragma unroll
    for (int tn = 0; tn < 8; tn++) obv[tn] = ob[16*tn + l15];
    #pragma unroll
    for (int tq = 0; tq < 2; tq++) {
        #pragma unroll
        for (int r = 0; r < 4; r++) {
            int qrow = 32*wv + 16*tq + 4*g16 + r;
            int g = mq[w * WIN + qrow];
            if (g < 0) continue;
            float* orow = x1 + (size_t)g * DM;
            #pragma unroll
            for (int tn = 0; tn < 8; tn++)
                orow[16*tn + l15] += oc[tq][tn][r] + obv[tn];
        }
    }
}

// ---------------- fused LN1 + FFN + residual + LN2 (64 rows/block, 16 rows/wave) ----------------
__global__ __launch_bounds__(256, 4) void k_ffn(
    const float* __restrict__ x1, const bf16* __restrict__ whi, const bf16* __restrict__ wlo,
    const float* __restrict__ g1, const float* __restrict__ b1ln,
    const float* __restrict__ fb1, const float* __restrict__ fb2,
    const float* __restrict__ g2, const float* __restrict__ b2ln,
    float* __restrict__ out)
{
    const int tid = threadIdx.x;
    const int lane = tid & 63, wv = tid >> 6;
    const int l15 = lane & 15, g16 = lane >> 4;
    const int rbase = blockIdx.x * 64 + wv * 16;
    __shared__ bf16 Hb[4][16 * 264];
    bf16* myH = &Hb[wv][0];
    const bf16* W1h = whi + 65536;
    const bf16* W2h = whi + 98304;

    // ---- LN1 stats: lane owns row rbase+l15, 32 of its cols ----
    float xv[4][8];
    float sum = 0.f, sq = 0.f;
    const float* xrow = x1 + (size_t)(rbase + l15) * DM;
    #pragma unroll
    for (int ks = 0; ks < 4; ks++) {
        float4 a = *(const float4*)(xrow + ks*32 + g16*8);
        float4 b = *(const float4*)(xrow + ks*32 + g16*8 + 4);
        xv[ks][0]=a.x; xv[ks][1]=a.y; xv[ks][2]=a.z; xv[ks][3]=a.w;
        xv[ks][4]=b.x; xv[ks][5]=b.y; xv[ks][6]=b.z; xv[ks][7]=b.w;
        sum += a.x+a.y+a.z+a.w + b.x+b.y+b.z+b.w;
        sq  += a.x*a.x+a.y*a.y+a.z*a.z+a.w*a.w + b.x*b.x+b.y*b.y+b.z*b.z+b.w*b.w;
    }
    sum += __shfl_xor(sum, 16); sum += __shfl_xor(sum, 32);
    sq  += __shfl_xor(sq, 16);  sq  += __shfl_xor(sq, 32);
    float mean = sum * (1.f/128.f);
    float var  = sq * (1.f/128.f) - mean * mean;
    float rstd = rsqrtf(var + 1e-5f);

    // ---- y = LN1(x) in f32 -> bf16 A-frags ----
    bf16x8 ah[4];
    #pragma unroll
    for (int ks = 0; ks < 4; ks++) {
        #pragma unroll
        for (int j = 0; j < 8; j++) {
            int col = ks*32 + g16*8 + j;
            float y = (xv[ks][j] - mean) * rstd * g1[col] + b1ln[col];
            ah[ks][j] = (bf16)y;
        }
    }

    // ---- GEMM1 + ReLU -> Hb, in two 8-tn chunks (acc = 32 VGPR) ----
    #pragma unroll
    for (int c = 0; c < 2; c++) {
        f32x4 h1[8];
        #pragma unroll
        for (int t = 0; t < 8; t++) h1[t] = {};
        #pragma unroll
        for (int ks = 0; ks < 4; ks++) {
            #pragma unroll
            for (int t = 0; t < 8; t++) {
                bf16x8 bh = *(const bf16x8*)(W1h + (size_t)(16*(8*c + t) + l15) * DM + ks*32 + g16*8);
                h1[t] = MFMA16(ah[ks], bh, h1[t]);
            }
        }
        #pragma unroll
        for (int t = 0; t < 8; t++) {
            int tn = 8*c + t;
            float bias = fb1[16*tn + l15];
            #pragma unroll
            for (int r = 0; r < 4; r++) {
                float v = fmaxf(h1[t][r] + bias, 0.f);
                myH[(4*g16 + r) * 264 + 16*tn + l15] = (bf16)v;
            }
        }
    }

    // ---- GEMM2 (plain bf16) ----
    f32x4 o[8];
    #pragma unroll
    for (int tn = 0; tn < 8; tn++) o[tn] = {};
    #pragma unroll
    for (int ks = 0; ks < 8; ks++) {
        bf16x8 a = *(const bf16x8*)(myH + l15 * 264 + ks*32 + g16*8);
        #pragma unroll
        for (int tn = 0; tn < 8; tn++) {
            bf16x8 bh = *(const bf16x8*)(W2h + (size_t)(16*tn + l15) * 256 + ks*32 + g16*8);
            o[tn] = MFMA16(a, bh, o[tn]);
        }
    }

    // ---- residual: recompute y for C-layout rows (exact f32), + LN2 ----
    #pragma unroll
    for (int r = 0; r < 4; r++) {
        int rw = 4*g16 + r;                       // row within wave tile
        int row = rbase + rw;
        float bm = __shfl(mean, rw);              // stats live in lanes 0..15
        float br = __shfl(rstd, rw);
        float tmp[8];
        float s2 = 0.f, q2 = 0.f;
        #pragma unroll
        for (int tn = 0; tn < 8; tn++) {
            int col = 16*tn + l15;
            float xr = x1[(size_t)row * DM + col];
            float y  = (xr - bm) * br * g1[col] + b1ln[col];
            float v  = o[tn][r] + fb2[col] + y;
            tmp[tn] = v; s2 += v; q2 += v * v;
        }
        #pragma unroll
        for (int d = 1; d <= 8; d <<= 1) { s2 += __shfl_xor(s2, d); q2 += __shfl_xor(q2, d); }
        float mean2 = s2 * (1.f/128.f);
        float var2  = q2 * (1.f/128.f) - mean2 * mean2;
        float rstd2 = rsqrtf(var2 + 1e-5f);
        #pragma unroll
        for (int tn = 0; tn < 8; tn++) {
            int col = 16*tn + l15;
            out[(size_t)row * DM + col] = (tmp[tn] - mean2) * rstd2 * g2[col] + b2ln[col];
        }
    }
}

// ---------------- launcher ----------------
extern "C" void kernel_launch(void* const* d_in, const int* in_sizes, int n_in,
                              void* d_out, int out_size, void* d_ws, size_t ws_size,
                              hipStream_t stream)
{
    const float* src      = (const float*)d_in[0];
    const float* src_prv  = (const float*)d_in[1];
    const float* pos      = (const float*)d_in[2];
    const float* pos_prv  = (const float*)d_in[3];
    const float* inpw     = (const float*)d_in[4];
    const float* inpb     = (const float*)d_in[5];
    const float* outpw    = (const float*)d_in[6];
    const float* outpb    = (const float*)d_in[7];
    const float* l1w      = (const float*)d_in[8];
    const float* l1b      = (const float*)d_in[9];
    const float* l2w      = (const float*)d_in[10];
    const float* l2b      = (const float*)d_in[11];
    const float* ln1g     = (const float*)d_in[12];
    const float* ln1b     = (const float*)d_in[13];
    const float* ln2g     = (const float*)d_in[14];
    const float* ln2b     = (const float*)d_in[15];
    const int* keep       = (const int*)d_in[16];
    const int* keep_p     = (const int*)d_in[17];
    const int* inds       = (const int*)d_in[18];
    const int* inds_p     = (const int*)d_in[19];
    const int n_inds = in_sizes[18], n_prv = in_sizes[19];

    char* wsb = (char*)d_ws;
    bf16* whi  = (bf16*)(wsb);                                  // 262144 B
    bf16* wlo  = (bf16*)(wsb + 262144);                         // 262144 B
    int*  mq   = (int*)(wsb + 524288);                          // 524288 B
    int*  mkv  = (int*)(wsb + 1048576);                         // 524288 B
    bf16* Qb   = (bf16*)(wsb + 1572864);                        // 33554432 B
    bf16* Kb   = (bf16*)(wsb + 1572864 + 33554432);             // 33554432 B
    bf16* Vtb  = (bf16*)(wsb + 1572864 + 2u*33554432);          // 33554432 B
    unsigned char* kmask = (unsigned char*)(wsb + 1572864 + 3u*33554432);  // 131072 B
    int* mflag = (int*)(wsb + 1572864 + 3u*33554432 + 131072);  // 4 B
    float* x1 = (float*)d_out;

    int mmax = n_inds > n_prv ? n_inds : n_prv;
    if (mmax < 32768) mmax = 32768;
    k_prep1<<<512, 256, 0, stream>>>(inpw, outpw, l1w, l2w, whi, wlo, mq, mkv, mflag);
    k_prep2<<<(mmax + 255) / 256, 256, 0, stream>>>((const int*)d_in[20], mflag,
                                                    inds, keep, n_inds, inds_p, keep_p, n_prv, mq, mkv);
    k_prep3<<<2048, 256, 0, stream>>>((const int*)d_in[20], (const unsigned char*)d_in[20], mflag, kmask,
                                      (const float4*)src, (float4*)x1, NTOT * DM / 4);
    k_qkv<<<NTOT / 64, 256, 0, stream>>>(src, src_prv, pos, pos_prv, whi, inpb, mq, mkv, Qb, Kb, Vtb);
    k_attn<<<NWIN, 256, 0, stream>>>(Qb, Kb, Vtb, whi, wlo, outpb, kmask, mq, x1);
    k_ffn<<<NTOT / 64, 256, 0, stream>>>(x1, whi, wlo, ln1g, ln1b, l1b, l2b, ln2g, ln2b, (float*)d_out);
}

// Round 11
// 454.406 us; speedup vs baseline: 1.5652x; 1.0504x over previous
//
#include <hip/hip_runtime.h>

#define NWIN 1024
#define WIN 128
#define DM 128
#define NTOT (NWIN*WIN)

typedef __bf16 bf16;
typedef __bf16 bf16x2 __attribute__((ext_vector_type(2)));
typedef __bf16 bf16x4 __attribute__((ext_vector_type(4)));
typedef __bf16 bf16x8 __attribute__((ext_vector_type(8)));
typedef float f32x4 __attribute__((ext_vector_type(4)));
typedef float f32x16 __attribute__((ext_vector_type(16)));

#define MFMA16(a,b,c) __builtin_amdgcn_mfma_f32_16x16x32_bf16(a,b,c,0,0,0)
#define MFMA32(a,b,c) __builtin_amdgcn_mfma_f32_32x32x16_bf16(a,b,c,0,0,0)

// scores scale (1/sqrt(16)) * log2(e), folded into Wq/bq so k_attn uses raw exp2
#define QSCALE 0.36067376022224085f

// ---------------- prep kernels (merged: 3 launches) ----------------

// grid 512: weights->bf16 (131072; Wq region pre-scaled by QSCALE), maps init, flag=0
__global__ void k_prep1(const float* __restrict__ inproj, const float* __restrict__ outproj,
                        const float* __restrict__ w1, const float* __restrict__ w2,
                        bf16* __restrict__ whi,
                        int* __restrict__ mq, int* __restrict__ mkv, int* __restrict__ flag) {
    int i = blockIdx.x * 256 + threadIdx.x;
    if (i == 0) *flag = 0;
    float v;
    if (i < 49152)       v = inproj[i];
    else if (i < 65536)  v = outproj[i - 49152];
    else if (i < 98304)  v = w1[i - 65536];
    else                 v = w2[i - 98304];
    if (i < 16384) v *= QSCALE;          // Wq rows: fold 0.25*log2(e) into Q
    whi[i] = (bf16)v;
    mq[i] = -1; mkv[i] = -1;
}

// grid covers max(n_inds, n_prv, 32768): mask-mode detect + scatter-map fill
__global__ void k_prep2(const int* __restrict__ kpm_i, int* __restrict__ flag,
                        const int* __restrict__ inds, const int* __restrict__ keep, int n,
                        const int* __restrict__ inds_p, const int* __restrict__ keep_p, int np,
                        int* __restrict__ mq, int* __restrict__ mkv) {
    int j = blockIdx.x * 256 + threadIdx.x;
    if (j < 32768) {
        int v = kpm_i[j];
        if (v != 0 && v != 1) atomicOr(flag, 1);
    }
    if (j < n)  mq[inds[j]]    = keep[j];
    if (j < np) mkv[inds_p[j]] = keep_p[j];
}

// grid 2048: mask expand (131072) + src->x1 copy (grid-stride float4)
__global__ void k_prep3(const int* __restrict__ kpm_i, const unsigned char* __restrict__ kpm_b,
                        const int* __restrict__ flag, unsigned char* __restrict__ kmask,
                        const float4* __restrict__ s, float4* __restrict__ d, int n4) {
    int i = blockIdx.x * 256 + threadIdx.x;
    if (i < 131072) {
        int byte_mode = *flag;
        kmask[i] = byte_mode ? (kpm_b[i] != 0) : (kpm_i[i] != 0);
    }
    int stride = gridDim.x * 256;
    for (int k = i; k < n4; k += stride) d[k] = s[k];
}

// Plain-bf16 GEMM (one 16-row tile): acc += A @ W^T.
__device__ __forceinline__ void proj1p(const bf16* __restrict__ Xh,
                                       const bf16* __restrict__ WH,
                                       int l15, int g16, f32x4 acc[8]) {
    #pragma unroll
    for (int ks = 0; ks < 4; ks++) {
        bf16x8 ah = *(const bf16x8*)(Xh + l15 * 136 + ks*32 + g16*8);
        #pragma unroll
        for (int tn = 0; tn < 8; tn++) {
            bf16x8 bh = *(const bf16x8*)(WH + (size_t)(16*tn + l15) * DM + ks*32 + g16*8);
            acc[tn] = MFMA16(ah, bh, acc[tn]);
        }
    }
}

// ---------------- QKV projection (64-row panel per block), plain bf16 ----------------
__global__ __launch_bounds__(256, 4) void k_qkv(
    const float* __restrict__ src, const float* __restrict__ src_prv,
    const float* __restrict__ pos, const float* __restrict__ pos_prv,
    const bf16* __restrict__ whi,
    const float* __restrict__ bqkv,
    const int* __restrict__ mq, const int* __restrict__ mkv,
    bf16* __restrict__ Qg, bf16* __restrict__ Kg, bf16* __restrict__ Vtg)
{
    const int blk = blockIdx.x;            // 2048 blocks, 64 rows each
    const int rbase = blk * 64;
    const int w = blk >> 1;                // window index
    const int kb = (blk & 1) * 64;         // key offset within window
    const int tid = threadIdx.x;
    const int lane = tid & 63, wv = tid >> 6;
    const int l15 = lane & 15, g16 = lane >> 4;
    __shared__ bf16 Xhi[64*136];
    __shared__ bf16 Bb[9216];              // Q/K staging [64][136] or Vt staging [128][72]

    const int srow = tid >> 2, sq4 = tid & 3;   // 4 threads per row, 32 cols each
    const int p = rbase + srow;
    const int gq = mq[p];
    const int gv = mkv[p];

    // ---- issue x_q loads AND prefetch x_v gather (regs) ----
    float4 aq[8], bq[8], vv[8];
    {
        const float4* pr = (const float4*)(pos + (size_t)p * DM + sq4 * 32);
        #pragma unroll
        for (int i = 0; i < 8; i++) aq[i] = pr[i];
        if (gq >= 0) {
            const float4* sr = (const float4*)(src + (size_t)gq * DM + sq4 * 32);
            #pragma unroll
            for (int i = 0; i < 8; i++) bq[i] = sr[i];
        }
        if (gv >= 0) {
            const float4* vr = (const float4*)(src_prv + (size_t)gv * DM + sq4 * 32);
            #pragma unroll
            for (int i = 0; i < 8; i++) vv[i] = vr[i];
        }
        bf16* xh = Xhi + srow * 136 + sq4 * 32;
        #pragma unroll
        for (int i = 0; i < 8; i++) {
            float4 v = aq[i];
            if (gq >= 0) { v.x += bq[i].x; v.y += bq[i].y; v.z += bq[i].z; v.w += bq[i].w; }
            bf16x4 h = { (bf16)v.x, (bf16)v.y, (bf16)v.z, (bf16)v.w };
            *(bf16x4*)(xh + i * 4) = h;
        }
    }
    __syncthreads();

    // ---- GEMM Q (wave wv owns rows 16*wv..+15); bias scaled to match Wq ----
    f32x4 qa[8];
    for (int tn = 0; tn < 8; tn++) qa[tn] = {};
    proj1p(Xhi + 16*wv*136, whi, l15, g16, qa);
    #pragma unroll
    for (int tn = 0; tn < 8; tn++) {
        float bias = bqkv[16*tn + l15] * QSCALE;
        #pragma unroll
        for (int r = 0; r < 4; r++)
            Bb[(16*wv + 4*g16 + r) * 136 + 16*tn + l15] = (bf16)(qa[tn][r] + bias);
    }
    // ---- prefetch pos_prv (regs), hidden under Q-store + GEMM V ----
    float4 pp[8];
    {
        const float4* ppr = (const float4*)(pos_prv + (size_t)p * DM + sq4 * 32);
        #pragma unroll
        for (int i = 0; i < 8; i++) pp[i] = ppr[i];
    }
    __syncthreads();   // X reads done; Bb(Q) written

    // ---- write x_v (prefetched) to X; store Q from Bb ----
    {
        bf16* xh = Xhi + srow * 136 + sq4 * 32;
        if (gv >= 0) {
            #pragma unroll
            for (int i = 0; i < 8; i++) {
                bf16x4 h = { (bf16)vv[i].x, (bf16)vv[i].y, (bf16)vv[i].z, (bf16)vv[i].w };
                *(bf16x4*)(xh + i * 4) = h;
            }
        } else {
            bf16x4 z = { (bf16)0.f, (bf16)0.f, (bf16)0.f, (bf16)0.f };
            #pragma unroll
            for (int i = 0; i < 8; i++) *(bf16x4*)(xh + i * 4) = z;
        }
    }
    #pragma unroll
    for (int it = 0; it < 4; it++) {
        int c = it * 256 + tid;
        int row = c >> 4, off = (c & 15) * 8;
        *(bf16x8*)(Qg + (size_t)(rbase + row) * DM + off) = *(const bf16x8*)(Bb + row*136 + off);
    }
    __syncthreads();   // x_v staged; Bb(Q) reads done

    // ---- GEMM V ----
    f32x4 va[8];
    for (int tn = 0; tn < 8; tn++) va[tn] = {};
    proj1p(Xhi + 16*wv*136, whi + 256*DM, l15, g16, va);
    #pragma unroll
    for (int tn = 0; tn < 8; tn++) {
        float bias = bqkv[256 + 16*tn + l15];
        int dim = 16*tn + l15;
        bf16x4 b = { (bf16)(va[tn][0] + bias), (bf16)(va[tn][1] + bias),
                     (bf16)(va[tn][2] + bias), (bf16)(va[tn][3] + bias) };
        *(bf16x4*)(Bb + dim * 72 + 16*wv + 4*g16) = b;   // Vt staging [128][72]
    }
    __syncthreads();   // X reads done; Bb(Vt) written

    // ---- X += pos_prv (prefetched regs); store Vt from Bb ----
    {
        bf16* xh = Xhi + srow * 136 + sq4 * 32;
        #pragma unroll
        for (int i = 0; i < 8; i++) {
            bf16x4 ch = *(const bf16x4*)(xh + i * 4);
            bf16x4 h = { (bf16)((float)ch.x + pp[i].x), (bf16)((float)ch.y + pp[i].y),
                         (bf16)((float)ch.z + pp[i].z), (bf16)((float)ch.w + pp[i].w) };
            *(bf16x4*)(xh + i * 4) = h;
        }
    }
    #pragma unroll
    for (int it = 0; it < 4; it++) {
        int c = it * 256 + tid;
        int dim = c >> 3, off = (c & 7) * 8;
        *(bf16x8*)(Vtg + ((size_t)w * 128 + dim) * 128 + kb + off) = *(const bf16x8*)(Bb + dim*72 + off);
    }
    __syncthreads();   // x_k staged; Bb(Vt) reads done

    // ---- GEMM K ----
    f32x4 ka[8];
    for (int tn = 0; tn < 8; tn++) ka[tn] = {};
    proj1p(Xhi + 16*wv*136, whi + 128*DM, l15, g16, ka);
    #pragma unroll
    for (int tn = 0; tn < 8; tn++) {
        float bias = bqkv[128 + 16*tn + l15];
        #pragma unroll
        for (int r = 0; r < 4; r++)
            Bb[(16*wv + 4*g16 + r) * 136 + 16*tn + l15] = (bf16)(ka[tn][r] + bias);
    }
    __syncthreads();
    #pragma unroll
    for (int it = 0; it < 4; it++) {
        int c = it * 256 + tid;
        int row = c >> 4, off = (c & 15) * 8;
        *(bf16x8*)(Kg + (size_t)(rbase + row) * DM + off) = *(const bf16x8*)(Bb + row*136 + off);
    }
}

// ---------------- attention + out_proj + scatter-add (per window) ----------------
// Scores arrive pre-scaled in log2 domain (Wq folded); mask is additive; exp2f direct.
__global__ __launch_bounds__(256) void k_attn(
    const bf16* __restrict__ Qg, const bf16* __restrict__ Kg, const bf16* __restrict__ Vtg,
    const bf16* __restrict__ whi, const float* __restrict__ ob,
    const unsigned char* __restrict__ kmask, const int* __restrict__ mq,
    float* __restrict__ x1)
{
    const int w = blockIdx.x;
    const int tid = threadIdx.x;
    const int lane = tid & 63, wv = tid >> 6;
    const int l15 = lane & 15, g16 = lane >> 4;
    const int l31 = lane & 31, h32 = lane >> 5;
    __shared__ bf16 P[4][32 * 136];
    bf16* myP = &P[wv][0];

    float mval[4];
    #pragma unroll
    for (int kt = 0; kt < 4; kt++) mval[kt] = kmask[w * WIN + 32*kt + l31] ? -1e9f : 0.f;

    const bf16* Qw = Qg + (size_t)w * WIN * DM;
    const bf16* Kw = Kg + (size_t)w * WIN * DM;
    const bf16* Vw = Vtg + (size_t)w * WIN * DM;

    f32x4 oacc[8][2];
    for (int h = 0; h < 8; h++) { oacc[h][0] = {}; oacc[h][1] = {}; }

    #pragma unroll
    for (int h = 0; h < 8; h++) {
        // S = Q_h @ K_h^T  (32 query rows per wave, 4 key tiles, K=16 per MFMA)
        bf16x8 qf = *(const bf16x8*)(Qw + (size_t)(32*wv + l31) * DM + 16*h + h32*8);
        f32x16 s[4];
        #pragma unroll
        for (int kt = 0; kt < 4; kt++) {
            bf16x8 kf = *(const bf16x8*)(Kw + (size_t)(32*kt + l31) * DM + 16*h + h32*8);
            f32x16 z = {};
            s[kt] = MFMA32(qf, kf, z);
        }
        // row softmax in log2 domain (row = (r&3)+8*(r>>2)+4*h32, cols = 32 lanes x 4 tiles)
        #pragma unroll
        for (int r = 0; r < 16; r++) {
            float s0 = s[0][r] + mval[0];
            float s1 = s[1][r] + mval[1];
            float s2 = s[2][r] + mval[2];
            float s3 = s[3][r] + mval[3];
            float m = fmaxf(fmaxf(s0, s1), fmaxf(s2, s3));
            #pragma unroll
            for (int d = 1; d <= 16; d <<= 1) m = fmaxf(m, __shfl_xor(m, d));
            float e0 = exp2f(s0 - m), e1 = exp2f(s1 - m);
            float e2 = exp2f(s2 - m), e3 = exp2f(s3 - m);
            float sum = e0 + e1 + e2 + e3;
            #pragma unroll
            for (int d = 1; d <= 16; d <<= 1) sum += __shfl_xor(sum, d);
            float inv = __builtin_amdgcn_rcpf(sum);
            int qrow = (r & 3) + 8 * (r >> 2) + 4 * h32;
            myP[qrow * 136 +      l31] = (bf16)(e0 * inv);
            myP[qrow * 136 + 32 + l31] = (bf16)(e1 * inv);
            myP[qrow * 136 + 64 + l31] = (bf16)(e2 * inv);
            myP[qrow * 136 + 96 + l31] = (bf16)(e3 * inv);
        }
        // O_h += P @ V_h   (B-operand = Vt rows, 8 contiguous keys)
        #pragma unroll
        for (int ks = 0; ks < 4; ks++) {
            bf16x8 p0 = *(const bf16x8*)(myP + (l15     ) * 136 + ks*32 + g16*8);
            bf16x8 p1 = *(const bf16x8*)(myP + (16 + l15) * 136 + ks*32 + g16*8);
            bf16x8 vf = *(const bf16x8*)(Vw + (size_t)(16*h + l15) * DM + ks*32 + g16*8);
            oacc[h][0] = MFMA16(p0, vf, oacc[h][0]);
            oacc[h][1] = MFMA16(p1, vf, oacc[h][1]);
        }
    }

    // O -> LDS (reuse P region), then out_proj (plain bf16 Wo)
    #pragma unroll
    for (int h = 0; h < 8; h++) {
        #pragma unroll
        for (int tq = 0; tq < 2; tq++) {
            #pragma unroll
            for (int r = 0; r < 4; r++)
                myP[(16*tq + 4*g16 + r) * 136 + 16*h + l15] = (bf16)oacc[h][tq][r];
        }
    }

    const bf16* Woh = whi + 49152;
    f32x4 oc[2][8];
    for (int tq = 0; tq < 2; tq++)
        for (int tn = 0; tn < 8; tn++)
            oc[tq][tn] = {};
    #pragma unroll
    for (int ks = 0; ks < 4; ks++) {
        bf16x8 a0 = *(const bf16x8*)(myP + (l15     ) * 136 + ks*32 + g16*8);
        bf16x8 a1 = *(const bf16x8*)(myP + (16 + l15) * 136 + ks*32 + g16*8);
        #pragma unroll
        for (int tn = 0; tn < 8; tn++) {
            bf16x8 bh = *(const bf16x8*)(Woh + (size_t)(16*tn + l15) * DM + ks*32 + g16*8);
            oc[0][tn] = MFMA16(a0, bh, oc[0][tn]);
            oc[1][tn] = MFMA16(a1, bh, oc[1][tn]);
        }
    }

    float obv[8];
    #pragma unroll
    for (int tn = 0; tn < 8; tn++) obv[tn] = ob[16*tn + l15];
    #pragma unroll
    for (int tq = 0; tq < 2; tq++) {
        #pragma unroll
        for (int r = 0; r < 4; r++) {
            int qrow = 32*wv + 16*tq + 4*g16 + r;
            int g = mq[w * WIN + qrow];
            if (g < 0) continue;
            float* orow = x1 + (size_t)g * DM;
            #pragma unroll
            for (int tn = 0; tn < 8; tn++)
                orow[16*tn + l15] += oc[tq][tn][r] + obv[tn];
        }
    }
}

// ---------------- fused LN1 + FFN + residual + LN2 (64 rows/block, 16 rows/wave) ----------------
__global__ __launch_bounds__(256, 4) void k_ffn(
    const float* __restrict__ x1, const bf16* __restrict__ whi,
    const float* __restrict__ g1, const float* __restrict__ b1ln,
    const float* __restrict__ fb1, const float* __restrict__ fb2,
    const float* __restrict__ g2, const float* __restrict__ b2ln,
    float* __restrict__ out)
{
    const int tid = threadIdx.x;
    const int lane = tid & 63, wv = tid >> 6;
    const int l15 = lane & 15, g16 = lane >> 4;
    const int rbase = blockIdx.x * 64 + wv * 16;
    __shared__ bf16 Hb[4][16 * 264];
    bf16* myH = &Hb[wv][0];
    const bf16* W1h = whi + 65536;
    const bf16* W2h = whi + 98304;

    // ---- LN1 stats: lane owns row rbase+l15, 32 of its cols ----
    float xv[4][8];
    float sum = 0.f, sq = 0.f;
    const float* xrow = x1 + (size_t)(rbase + l15) * DM;
    #pragma unroll
    for (int ks = 0; ks < 4; ks++) {
        float4 a = *(const float4*)(xrow + ks*32 + g16*8);
        float4 b = *(const float4*)(xrow + ks*32 + g16*8 + 4);
        xv[ks][0]=a.x; xv[ks][1]=a.y; xv[ks][2]=a.z; xv[ks][3]=a.w;
        xv[ks][4]=b.x; xv[ks][5]=b.y; xv[ks][6]=b.z; xv[ks][7]=b.w;
        sum += a.x+a.y+a.z+a.w + b.x+b.y+b.z+b.w;
        sq  += a.x*a.x+a.y*a.y+a.z*a.z+a.w*a.w + b.x*b.x+b.y*b.y+b.z*b.z+b.w*b.w;
    }
    sum += __shfl_xor(sum, 16); sum += __shfl_xor(sum, 32);
    sq  += __shfl_xor(sq, 16);  sq  += __shfl_xor(sq, 32);
    float mean = sum * (1.f/128.f);
    float var  = sq * (1.f/128.f) - mean * mean;
    float rstd = rsqrtf(var + 1e-5f);

    // ---- y = LN1(x) in f32 -> bf16 A-frags ----
    bf16x8 ah[4];
    #pragma unroll
    for (int ks = 0; ks < 4; ks++) {
        #pragma unroll
        for (int j = 0; j < 8; j++) {
            int col = ks*32 + g16*8 + j;
            float y = (xv[ks][j] - mean) * rstd * g1[col] + b1ln[col];
            ah[ks][j] = (bf16)y;
        }
    }

    // ---- GEMM1 + ReLU -> Hb, in two 8-tn chunks (acc = 32 VGPR) ----
    #pragma unroll
    for (int c = 0; c < 2; c++) {
        f32x4 h1[8];
        #pragma unroll
        for (int t = 0; t < 8; t++) h1[t] = {};
        #pragma unroll
        for (int ks = 0; ks < 4; ks++) {
            #pragma unroll
            for (int t = 0; t < 8; t++) {
                bf16x8 bh = *(const bf16x8*)(W1h + (size_t)(16*(8*c + t) + l15) * DM + ks*32 + g16*8);
                h1[t] = MFMA16(ah[ks], bh, h1[t]);
            }
        }
        #pragma unroll
        for (int t = 0; t < 8; t++) {
            int tn = 8*c + t;
            float bias = fb1[16*tn + l15];
            #pragma unroll
            for (int r = 0; r < 4; r++) {
                float v = fmaxf(h1[t][r] + bias, 0.f);
                myH[(4*g16 + r) * 264 + 16*tn + l15] = (bf16)v;
            }
        }
    }

    // ---- GEMM2 (plain bf16) ----
    f32x4 o[8];
    #pragma unroll
    for (int tn = 0; tn < 8; tn++) o[tn] = {};
    #pragma unroll
    for (int ks = 0; ks < 8; ks++) {
        bf16x8 a = *(const bf16x8*)(myH + l15 * 264 + ks*32 + g16*8);
        #pragma unroll
        for (int tn = 0; tn < 8; tn++) {
            bf16x8 bh = *(const bf16x8*)(W2h + (size_t)(16*tn + l15) * 256 + ks*32 + g16*8);
            o[tn] = MFMA16(a, bh, o[tn]);
        }
    }

    // ---- residual: recompute y for C-layout rows (exact f32), + LN2 ----
    #pragma unroll
    for (int r = 0; r < 4; r++) {
        int rw = 4*g16 + r;                       // row within wave tile
        int row = rbase + rw;
        float bm = __shfl(mean, rw);              // stats live in lanes 0..15
        float br = __shfl(rstd, rw);
        float tmp[8];
        float s2 = 0.f, q2 = 0.f;
        #pragma unroll
        for (int tn = 0; tn < 8; tn++) {
            int col = 16*tn + l15;
            float xr = x1[(size_t)row * DM + col];
            float y  = (xr - bm) * br * g1[col] + b1ln[col];
            float v  = o[tn][r] + fb2[col] + y;
            tmp[tn] = v; s2 += v; q2 += v * v;
        }
        #pragma unroll
        for (int d = 1; d <= 8; d <<= 1) { s2 += __shfl_xor(s2, d); q2 += __shfl_xor(q2, d); }
        float mean2 = s2 * (1.f/128.f);
        float var2  = q2 * (1.f/128.f) - mean2 * mean2;
        float rstd2 = rsqrtf(var2 + 1e-5f);
        #pragma unroll
        for (int tn = 0; tn < 8; tn++) {
            int col = 16*tn + l15;
            out[(size_t)row * DM + col] = (tmp[tn] - mean2) * rstd2 * g2[col] + b2ln[col];
        }
    }
}

// ---------------- launcher ----------------
extern "C" void kernel_launch(void* const* d_in, const int* in_sizes, int n_in,
                              void* d_out, int out_size, void* d_ws, size_t ws_size,
                              hipStream_t stream)
{
    const float* src      = (const float*)d_in[0];
    const float* src_prv  = (const float*)d_in[1];
    const float* pos      = (const float*)d_in[2];
    const float* pos_prv  = (const float*)d_in[3];
    const float* inpw     = (const float*)d_in[4];
    const float* inpb     = (const float*)d_in[5];
    const float* outpw    = (const float*)d_in[6];
    const float* outpb    = (const float*)d_in[7];
    const float* l1w      = (const float*)d_in[8];
    const float* l1b      = (const float*)d_in[9];
    const float* l2w      = (const float*)d_in[10];
    const float* l2b      = (const float*)d_in[11];
    const float* ln1g     = (const float*)d_in[12];
    const float* ln1b     = (const float*)d_in[13];
    const float* ln2g     = (const float*)d_in[14];
    const float* ln2b     = (const float*)d_in[15];
    const int* keep       = (const int*)d_in[16];
    const int* keep_p     = (const int*)d_in[17];
    const int* inds       = (const int*)d_in[18];
    const int* inds_p     = (const int*)d_in[19];
    const int n_inds = in_sizes[18], n_prv = in_sizes[19];

    char* wsb = (char*)d_ws;
    bf16* whi  = (bf16*)(wsb);                                  // 262144 B
    int*  mq   = (int*)(wsb + 524288);                          // 524288 B
    int*  mkv  = (int*)(wsb + 1048576);                         // 524288 B
    bf16* Qb   = (bf16*)(wsb + 1572864);                        // 33554432 B
    bf16* Kb   = (bf16*)(wsb + 1572864 + 33554432);             // 33554432 B
    bf16* Vtb  = (bf16*)(wsb + 1572864 + 2u*33554432);          // 33554432 B
    unsigned char* kmask = (unsigned char*)(wsb + 1572864 + 3u*33554432);  // 131072 B
    int* mflag = (int*)(wsb + 1572864 + 3u*33554432 + 131072);  // 4 B
    float* x1 = (float*)d_out;

    int mmax = n_inds > n_prv ? n_inds : n_prv;
    if (mmax < 32768) mmax = 32768;
    k_prep1<<<512, 256, 0, stream>>>(inpw, outpw, l1w, l2w, whi, mq, mkv, mflag);
    k_prep2<<<(mmax + 255) / 256, 256, 0, stream>>>((const int*)d_in[20], mflag,
                                                    inds, keep, n_inds, inds_p, keep_p, n_prv, mq, mkv);
    k_prep3<<<2048, 256, 0, stream>>>((const int*)d_in[20], (const unsigned char*)d_in[20], mflag, kmask,
                                      (const float4*)src, (float4*)x1, NTOT * DM / 4);
    k_qkv<<<NTOT / 64, 256, 0, stream>>>(src, src_prv, pos, pos_prv, whi, inpb, mq, mkv, Qb, Kb, Vtb);
    k_attn<<<NWIN, 256, 0, stream>>>(Qb, Kb, Vtb, whi, outpb, kmask, mq, x1);
    k_ffn<<<NTOT / 64, 256, 0, stream>>>(x1, whi, ln1g, ln1b, l1b, l2b, ln2g, ln2b, (float*)d_out);
}